// Round 12
// baseline (150.261 us; speedup 1.0000x reference)
//
#include <hip/hip_runtime.h>

#define DEV static __device__ __forceinline__

typedef __attribute__((ext_vector_type(8))) __bf16 bf16x8;
typedef __attribute__((ext_vector_type(4))) float f32x4;

constexpr int CB = 2;     // batch
constexpr int CS = 2048;  // seq
constexpr int CE = 1024;  // embed
constexpr int CH = 16;    // heads
constexpr int CD = 64;    // head dim
constexpr float LOG2E = 1.44269504f;

DEV unsigned short f2bf(float x) {  // RNE f32 -> bf16 bits
  unsigned int u = __float_as_uint(x);
  u += 0x7fffu + ((u >> 16) & 1u);
  return (unsigned short)(u >> 16);
}

DEV f32x4 mfma32(bf16x8 a, bf16x8 b, f32x4 c) {  // 16x16x32
  return __builtin_amdgcn_mfma_f32_16x16x32_bf16(a, b, c, 0, 0, 0);
}

DEV unsigned int cvtpk(float lo, float hi) {  // pack 2 f32 -> 2 bf16 (RNE)
  unsigned int r;
  asm("v_cvt_pk_bf16_f32 %0, %1, %2" : "=v"(r) : "v"(lo), "v"(hi));
  return r;
}

DEV float exp2r(float x) {  // raw v_exp_f32
#if __has_builtin(__builtin_amdgcn_exp2f)
  return __builtin_amdgcn_exp2f(x);
#else
  float r; asm("v_exp_f32 %0, %1" : "=v"(r) : "v"(x)); return r;
#endif
}

DEV f32x4 unpk(unsigned int a, unsigned int b) {  // 4 packed bf16 -> f32x4
  f32x4 r;
  r[0] = __uint_as_float(a << 16);
  r[1] = __uint_as_float(a & 0xffff0000u);
  r[2] = __uint_as_float(b << 16);
  r[3] = __uint_as_float(b & 0xffff0000u);
  return r;
}

DEV void stage16(const void* g, void* l) {  // async global(16B/lane) -> LDS
  __builtin_amdgcn_global_load_lds(
      (const __attribute__((address_space(1))) unsigned int*)g,
      (__attribute__((address_space(3))) unsigned int*)l, 16, 0, 0);
}

// ------- fused f32 -> bf16 convert: x | kv | WQ | WK | WV | WO -> contiguous ws -------
__global__ __launch_bounds__(256) void cvt_all(const float* __restrict__ x,
                                               const float* __restrict__ kv,
                                               const float* __restrict__ w0,
                                               const float* __restrict__ w1,
                                               const float* __restrict__ w2,
                                               const float* __restrict__ w3,
                                               unsigned short* __restrict__ out) {
  const long NE = (long)CB * CS * CE;
  const long WE = (long)CE * CE;
  long i = ((long)blockIdx.x * 256 + threadIdx.x) * 8;
  const float* src;
  long off = i;
  if (i < NE) {
    src = x;
  } else if (i < 2 * NE) {
    src = kv; off = i - NE;
  } else {
    long j = i - 2 * NE;
    int wi = (int)(j >> 20);
    src = wi == 0 ? w0 : wi == 1 ? w1 : wi == 2 ? w2 : w3;
    off = j & (WE - 1);
  }
  float4 a = *reinterpret_cast<const float4*>(src + off);
  float4 b = *reinterpret_cast<const float4*>(src + off + 4);
  uint4 v;
  v.x = (unsigned int)f2bf(a.x) | ((unsigned int)f2bf(a.y) << 16);
  v.y = (unsigned int)f2bf(a.z) | ((unsigned int)f2bf(a.w) << 16);
  v.z = (unsigned int)f2bf(b.x) | ((unsigned int)f2bf(b.y) << 16);
  v.w = (unsigned int)f2bf(b.z) | ((unsigned int)f2bf(b.w) << 16);
  *reinterpret_cast<uint4*>(out + i) = v;
}

// ------- mbias (bf16, log2 domain):
//   mq==0            -> 0            (q fully masked: uniform row, matches ref)
//   mq!=0 && mk==0   -> -1e9*log2e   (exp2 -> exact 0)
//   else             -> bias*log2e
__global__ __launch_bounds__(256) void mk_mbias(const float* __restrict__ bias,
                                                const int* __restrict__ mask,
                                                unsigned short* __restrict__ mb16) {
  const long idx = ((long)blockIdx.x * 256 + threadIdx.x) * 8;  // over CB*CS*CS
  const int b = (int)(idx >> 22);
  const int q = (int)((idx >> 11) & (CS - 1));
  const int k0 = (int)(idx & (CS - 1));
  const bool mq = mask[b * CS + q] != 0;
  const int4 mk0 = *reinterpret_cast<const int4*>(mask + b * CS + k0);
  const int4 mk1 = *reinterpret_cast<const int4*>(mask + b * CS + k0 + 4);
  const float4 b0 = *reinterpret_cast<const float4*>(bias + idx);
  const float4 b1 = *reinterpret_cast<const float4*>(bias + idx + 4);
  const float NEG = -1e9f * LOG2E;
  float v[8];
  if (mq) {
    v[0] = (mk0.x != 0) ? b0.x * LOG2E : NEG;
    v[1] = (mk0.y != 0) ? b0.y * LOG2E : NEG;
    v[2] = (mk0.z != 0) ? b0.z * LOG2E : NEG;
    v[3] = (mk0.w != 0) ? b0.w * LOG2E : NEG;
    v[4] = (mk1.x != 0) ? b1.x * LOG2E : NEG;
    v[5] = (mk1.y != 0) ? b1.y * LOG2E : NEG;
    v[6] = (mk1.z != 0) ? b1.z * LOG2E : NEG;
    v[7] = (mk1.w != 0) ? b1.w * LOG2E : NEG;
  } else {
#pragma unroll
    for (int j = 0; j < 8; j++) v[j] = 0.f;  // uniform row (qf also zeroed in attn)
  }
  uint4 o;
  o.x = cvtpk(v[0], v[1]); o.y = cvtpk(v[2], v[3]);
  o.z = cvtpk(v[4], v[5]); o.w = cvtpk(v[6], v[7]);
  *reinterpret_cast<uint4*>(mb16 + idx) = o;
}

// ---------------- fused QKV GEMM: [Q|K|V] = A @ W{q,k,v}^T + bias ----------------
__global__ __launch_bounds__(256) void gemm_qkv(const unsigned short* __restrict__ xb,
                                                const unsigned short* __restrict__ kvb,
                                                const unsigned short* __restrict__ Wall,
                                                const float* __restrict__ bq,
                                                const float* __restrict__ bk,
                                                const float* __restrict__ bv,
                                                unsigned short* __restrict__ Qb) {
  __shared__ __align__(16) unsigned short As[128 * 64];
  __shared__ __align__(16) unsigned short Bs[128 * 64];
  const long NE = (long)CB * CS * CE;
  const long WE = (long)CE * CE;
  const int which = blockIdx.y >> 3;           // 0=Q 1=K 2=V
  const int n0 = (blockIdx.y & 7) * 128;
  const unsigned short* A = which == 0 ? xb : kvb;
  const unsigned short* W = Wall + (long)which * WE;
  const float* bias = which == 0 ? bq : which == 1 ? bk : bv;
  const int tid = threadIdx.x;
  const int lane = tid & 63, wave = tid >> 6;
  const int wm = (wave >> 1) * 64, wn = (wave & 1) * 64;
  const int g = lane >> 4, rr = lane & 15;
  const int m0 = blockIdx.x * 128;
  const int K = CE;
  f32x4 acc[4][4] = {};

  for (int k0 = 0; k0 < K; k0 += 64) {
#pragma unroll
    for (int t = 0; t < 4; t++) {
      const int u = t * 256 + tid;
      const int row = u >> 3, ce = (u & 7) * 8;
      const int lb = (t * 256 + (tid & 192)) * 16;
      stage16(A + (long)(m0 + row) * K + k0 + ce, (char*)As + lb);
      stage16(W + (long)(n0 + row) * K + k0 + ce, (char*)Bs + lb);
    }
    __syncthreads();
#pragma unroll
    for (int kk = 0; kk < 2; kk++) {
      bf16x8 af[4], bfr[4];
#pragma unroll
      for (int i = 0; i < 4; i++)
        af[i] = *reinterpret_cast<const bf16x8*>(&As[(wm + i * 16 + rr) * 64 + kk * 32 + g * 8]);
#pragma unroll
      for (int j = 0; j < 4; j++)
        bfr[j] = *reinterpret_cast<const bf16x8*>(&Bs[(wn + j * 16 + rr) * 64 + kk * 32 + g * 8]);
#pragma unroll
      for (int i = 0; i < 4; i++)
#pragma unroll
        for (int j = 0; j < 4; j++)
          acc[i][j] = mfma32(af[i], bfr[j], acc[i][j]);
    }
    __syncthreads();
  }

  const float scale = which == 0 ? 0.125f * LOG2E : 1.0f;  // fold 1/sqrt(dk)*log2e into Q
#pragma unroll
  for (int i = 0; i < 4; i++) {
#pragma unroll
    for (int j = 0; j < 4; j++) {
      const int colg = n0 + wn + j * 16 + rr;
      const float bvv = bias[colg];
      if (which == 2) {  // V^T layout [B,H,DK,S]
        const int rowbase = m0 + wm + i * 16 + g * 4;
        const int bb = rowbase >> 11, s = rowbase & 2047;
        const int hh = colg >> 6, d = colg & 63;
        uint2 val;
        val.x = (unsigned int)f2bf(acc[i][j][0] + bvv) | ((unsigned int)f2bf(acc[i][j][1] + bvv) << 16);
        val.y = (unsigned int)f2bf(acc[i][j][2] + bvv) | ((unsigned int)f2bf(acc[i][j][3] + bvv) << 16);
        *reinterpret_cast<uint2*>(Qb + 2 * NE + ((long)((bb * CH + hh) * CD + d)) * CS + s) = val;
      } else {
        unsigned short* outp = Qb + (long)which * NE;
#pragma unroll
        for (int r = 0; r < 4; r++) {
          const int row = m0 + wm + i * 16 + g * 4 + r;
          outp[(long)row * CE + colg] = f2bf((acc[i][j][r] + bvv) * scale);
        }
      }
    }
  }
}

// ---------------- WO GEMM: out_f32 = A @ W^T + bias ----------------
__global__ __launch_bounds__(256) void gemm_wo(const unsigned short* __restrict__ A,
                                               const unsigned short* __restrict__ W,
                                               const float* __restrict__ bias,
                                               float* __restrict__ out) {
  __shared__ __align__(16) unsigned short As[128 * 64];
  __shared__ __align__(16) unsigned short Bs[128 * 64];
  const int tid = threadIdx.x;
  const int lane = tid & 63, wave = tid >> 6;
  const int wm = (wave >> 1) * 64, wn = (wave & 1) * 64;
  const int g = lane >> 4, rr = lane & 15;
  const int m0 = blockIdx.x * 128, n0 = blockIdx.y * 128;
  const int K = CE;
  f32x4 acc[4][4] = {};

  for (int k0 = 0; k0 < K; k0 += 64) {
#pragma unroll
    for (int t = 0; t < 4; t++) {
      const int u = t * 256 + tid;
      const int row = u >> 3, ce = (u & 7) * 8;
      const int lb = (t * 256 + (tid & 192)) * 16;
      stage16(A + (long)(m0 + row) * K + k0 + ce, (char*)As + lb);
      stage16(W + (long)(n0 + row) * K + k0 + ce, (char*)Bs + lb);
    }
    __syncthreads();
#pragma unroll
    for (int kk = 0; kk < 2; kk++) {
      bf16x8 af[4], bfr[4];
#pragma unroll
      for (int i = 0; i < 4; i++)
        af[i] = *reinterpret_cast<const bf16x8*>(&As[(wm + i * 16 + rr) * 64 + kk * 32 + g * 8]);
#pragma unroll
      for (int j = 0; j < 4; j++)
        bfr[j] = *reinterpret_cast<const bf16x8*>(&Bs[(wn + j * 16 + rr) * 64 + kk * 32 + g * 8]);
#pragma unroll
      for (int i = 0; i < 4; i++)
#pragma unroll
        for (int j = 0; j < 4; j++)
          acc[i][j] = mfma32(af[i], bfr[j], acc[i][j]);
    }
    __syncthreads();
  }

#pragma unroll
  for (int i = 0; i < 4; i++)
#pragma unroll
    for (int j = 0; j < 4; j++) {
      const int colg = n0 + wn + j * 16 + rr;
      const float bvv = bias[colg];
#pragma unroll
      for (int r = 0; r < 4; r++) {
        const int row = m0 + wm + i * 16 + g * 4 + r;
        out[(long)row * CE + colg] = acc[i][j][r] + bvv;
      }
    }
}

// ---------------- Flash attention v11: XCD co-location + 3 blocks/CU ----------------
// v10 structure (static softmax, permuted-K LDS, counted vmcnt(8)).
// Grid order (h, qt, b): linear id % 8 = h % 8 -> all 16 qt-blocks sharing a (b,h)
// K/V panel land on ONE XCD's L2 (kills K/V re-fetch); mbias sharers 2-way co-located.
// __launch_bounds__(256,3): cap unified VGPR ~168 -> 3 blocks/CU resident.
__global__ __launch_bounds__(256, 3) void attn_kernel(const unsigned short* __restrict__ Qb,
                                                      const unsigned short* __restrict__ Kb,
                                                      const unsigned short* __restrict__ Vtw,
                                                      const unsigned short* __restrict__ mb16,
                                                      const int* __restrict__ mask,
                                                      unsigned short* __restrict__ AO) {
  __shared__ __align__(16) unsigned char lds[32768];  // 2 x (K 8KB | V 8KB)
  const int h = blockIdx.x, qt = blockIdx.y, b = blockIdx.z;  // h fastest -> XCD co-location
  const int tid = threadIdx.x;
  const int lane = tid & 63, w = tid >> 6;
  const int g = lane >> 4, c = lane & 15;
  const int qbase = qt * 128 + w * 32;  // + qb*16 + c

  bf16x8 qf[2][2];  // [qb][kd]; B-frag col=c=q, k(d)=kd*32+g*8+j (Q pre-scaled 0.125*log2e)
#pragma unroll
  for (int qb = 0; qb < 2; qb++) {
    const unsigned short* Qrow = Qb + ((long)b * CS + qbase + qb * 16 + c) * CE + h * CD;
    qf[qb][0] = *reinterpret_cast<const bf16x8*>(Qrow + g * 8);
    qf[qb][1] = *reinterpret_cast<const bf16x8*>(Qrow + 32 + g * 8);
    if (mask[b * CS + qbase + qb * 16 + c] == 0) {  // uniform masked rows (mbias=0 there)
      qf[qb][0] = bf16x8{}; qf[qb][1] = bf16x8{};
    }
  }

  // stage sources (per-lane), induction-advanced per 64-key tile
  const unsigned char *kg0, *kg1, *vg0, *vg1;
  {
    const unsigned char* Ksrc = (const unsigned char*)(Kb + (long)b * CS * CE + h * CD);
    const unsigned char* Vsrc = (const unsigned char*)(Vtw + (long)(b * CH + h) * CD * CS);
    const int r0 = w * 8 + (lane >> 3), r1 = 32 + (w * 8 + (lane >> 3));
    const int cs = (lane & 7) << 4;
    const int c0 = cs ^ ((r0 & 7) << 4), c1 = cs ^ ((r1 & 7) << 4);
    // LDS row -> key permutation (PV B-frag order)
    const int k0 = (r0 & 32) + ((r0 >> 2) & 3) * 8 + ((r0 >> 4) & 1) * 4 + (r0 & 3);
    const int k1 = (r1 & 32) + ((r1 >> 2) & 3) * 8 + ((r1 >> 4) & 1) * 4 + (r1 & 3);
    kg0 = Ksrc + (long)k0 * (CE * 2) + c0;
    kg1 = Ksrc + (long)k1 * (CE * 2) + c1;
    vg0 = Vsrc + (long)r0 * (CS * 2) + c0;
    vg1 = Vsrc + (long)r1 * (CS * 2) + c1;
  }
  // LDS stage destinations (wave-uniform)
  unsigned char* sK0 = lds + w * 1024;
  unsigned char* sK1 = lds + 4096 + w * 1024;
  unsigned char* sV0 = lds + 8192 + w * 1024;
  unsigned char* sV1 = lds + 12288 + w * 1024;
  // LDS read bases (per-lane); all reads = base + 16-bit immediate
  const int sw = (c & 7) << 4;
  const unsigned char* rb0 = lds + c * 128 + ((g * 16) ^ sw);
  const unsigned char* rb1 = lds + c * 128 + ((64 + g * 16) ^ sw);

  // mbias running pointers per qb (+64 elements per real tile)
  const unsigned short* mbp0 = mb16 + ((long)b * CS + qbase + c) * CS + g * 8;
  const unsigned short* mbp1 = mb16 + ((long)b * CS + qbase + 16 + c) * CS + g * 8;

  f32x4 o[2][4] = {};
  f32x4 lsum4[2] = {};
  uint4 mbr[2][2];  // [qb][kb] 8 bf16 each: k = kb*32 + g*8 + j

  auto stage = [&](int bo) {  // 4 vmem ops; advances to next tile
    stage16(kg0, sK0 + bo); stage16(kg1, sK1 + bo);
    stage16(vg0, sV0 + bo); stage16(vg1, sV1 + bo);
    kg0 += 64 * CE * 2; kg1 += 64 * CE * 2;
    vg0 += 64 * 2; vg1 += 64 * 2;
  };
  auto load_mb = [&](bool adv) {  // 4 vmem ops (16B each)
    mbr[0][0] = *reinterpret_cast<const uint4*>(mbp0);
    mbr[0][1] = *reinterpret_cast<const uint4*>(mbp0 + 32);
    mbr[1][0] = *reinterpret_cast<const uint4*>(mbp1);
    mbr[1][1] = *reinterpret_cast<const uint4*>(mbp1 + 32);
    if (adv) { mbp0 += 64; mbp1 += 64; }
  };

  auto compute = [&](int bo, bool adv) {
    // ---- S^T: C-init = mbias (bf16 unpack), += K @ Q^T ----
    f32x4 sf[2][4];
    __builtin_amdgcn_s_setprio(1);
#pragma unroll
    for (int cb = 0; cb < 4; cb++) {
      const bf16x8 kf0 = *reinterpret_cast<const bf16x8*>(rb0 + bo + cb * 2048);
      const bf16x8 kf1 = *reinterpret_cast<const bf16x8*>(rb1 + bo + cb * 2048);
#pragma unroll
      for (int qb = 0; qb < 2; qb++) {
        const uint4 m = mbr[qb][cb >> 1];
        const f32x4 ci = (cb & 1) ? unpk(m.z, m.w) : unpk(m.x, m.y);
        f32x4 t = mfma32(kf0, qf[qb][0], ci);
        sf[qb][cb] = mfma32(kf1, qf[qb][1], t);
      }
    }
    __builtin_amdgcn_s_setprio(0);
    load_mb(adv);  // prefetch next tile's mbias (4 vmem)
    // ---- STATIC softmax: p = exp2(sf) straight through; no max, no rescale ----
    uint4 pw[2][2];
#pragma unroll
    for (int qb = 0; qb < 2; qb++)
#pragma unroll
      for (int kb = 0; kb < 2; kb++)
#pragma unroll
        for (int half = 0; half < 2; half++) {
          const int cb = 2 * kb + half;
          f32x4 pv;
          pv[0] = exp2r(sf[qb][cb][0]);
          pv[1] = exp2r(sf[qb][cb][1]);
          pv[2] = exp2r(sf[qb][cb][2]);
          pv[3] = exp2r(sf[qb][cb][3]);
          lsum4[qb] = lsum4[qb] + pv;
          if (half == 0) { pw[qb][kb].x = cvtpk(pv[0], pv[1]); pw[qb][kb].y = cvtpk(pv[2], pv[3]); }
          else           { pw[qb][kb].z = cvtpk(pv[0], pv[1]); pw[qb][kb].w = cvtpk(pv[2], pv[3]); }
        }
    // ---- O^T += V^T P^T (V frags shared across qb) ----
    __builtin_amdgcn_s_setprio(1);
#pragma unroll
    for (int nb = 0; nb < 4; nb++) {
      const bf16x8 vf0 = *reinterpret_cast<const bf16x8*>(rb0 + bo + 8192 + nb * 2048);
      const bf16x8 vf1 = *reinterpret_cast<const bf16x8*>(rb1 + bo + 8192 + nb * 2048);
#pragma unroll
      for (int qb = 0; qb < 2; qb++) {
        o[qb][nb] = mfma32(vf0, __builtin_bit_cast(bf16x8, pw[qb][0]), o[qb][nb]);
        o[qb][nb] = mfma32(vf1, __builtin_bit_cast(bf16x8, pw[qb][1]), o[qb][nb]);
      }
    }
    __builtin_amdgcn_s_setprio(0);
  };

  stage(0);         // tile 0 -> buf0  [4]
  load_mb(true);    // mb = tile 0     [4]
  stage(16384);     // tile 1 -> buf1  [4]

#pragma unroll 1
  for (int it = 0; it < 16; ++it) {  // 32 tiles of 64 keys
    // ---- tile t=2it (buf0) ----
    asm volatile("s_waitcnt vmcnt(8)" ::: "memory");  // retire stage(t)
    __builtin_amdgcn_s_barrier();
    __builtin_amdgcn_sched_barrier(0);
    compute(0, it < 15);                              // loads mb(t+1) inside
    __builtin_amdgcn_sched_barrier(0);
    __builtin_amdgcn_s_barrier();
    stage(0);                                         // tile t+2 (junk at tail, valid mem)
    // ---- tile t+1 (buf1) ----
    asm volatile("s_waitcnt vmcnt(8)" ::: "memory");
    __builtin_amdgcn_s_barrier();
    __builtin_amdgcn_sched_barrier(0);
    compute(16384, it < 15);                          // loads mb(t+2) inside (junk at tail)
    __builtin_amdgcn_sched_barrier(0);
    __builtin_amdgcn_s_barrier();
    stage(16384);                                     // tile t+3 (junk at tail, valid mem)
  }

#pragma unroll
  for (int qb = 0; qb < 2; qb++) {
    float lsum = (lsum4[qb][0] + lsum4[qb][1]) + (lsum4[qb][2] + lsum4[qb][3]);
    lsum += __shfl_xor(lsum, 16, 64);
    lsum += __shfl_xor(lsum, 32, 64);
    const float linv = 1.0f / lsum;
    unsigned short* Orow = AO + ((long)b * CS + qbase + qb * 16 + c) * CE + h * CD;
#pragma unroll
    for (int nb = 0; nb < 4; nb++) {
      uint2 val;
      val.x = (unsigned int)f2bf(o[qb][nb][0] * linv) | ((unsigned int)f2bf(o[qb][nb][1] * linv) << 16);
      val.y = (unsigned int)f2bf(o[qb][nb][2] * linv) | ((unsigned int)f2bf(o[qb][nb][3] * linv) << 16);
      *reinterpret_cast<uint2*>(Orow + nb * 16 + g * 4) = val;
    }
  }
  asm volatile("s_waitcnt vmcnt(0)" ::: "memory");  // drain junk stages before endpgm
}

// ---------------- host ----------------
extern "C" void kernel_launch(void* const* d_in, const int* in_sizes, int n_in,
                              void* d_out, int out_size, void* d_ws, size_t ws_size,
                              hipStream_t stream) {
  (void)in_sizes; (void)n_in; (void)out_size; (void)ws_size;
  const float* x    = (const float*)d_in[0];
  const float* kv   = (const float*)d_in[1];
  const int*   mask = (const int*)d_in[2];
  const float* ab   = (const float*)d_in[3];
  const float* WQw  = (const float*)d_in[4];
  const float* WQb  = (const float*)d_in[5];
  const float* WKw  = (const float*)d_in[6];
  const float* WKb  = (const float*)d_in[7];
  const float* WVw  = (const float*)d_in[8];
  const float* WVb  = (const float*)d_in[9];
  const float* WOw  = (const float*)d_in[10];
  const float* WOb  = (const float*)d_in[11];
  float* out = (float*)d_out;

  const long NE = (long)CB * CS * CE;  // 4,194,304
  const long WE = (long)CE * CE;       // 1,048,576
  unsigned short* ws  = (unsigned short*)d_ws;
  unsigned short* xb  = ws;            // [x | kv | WQ | WK | WV | WO] contiguous
  unsigned short* kvb = xb + NE;
  unsigned short* wqb = kvb + NE;      // WQ|WK|WV contiguous = Wall
  unsigned short* wob = wqb + 3 * WE;
  unsigned short* Qb  = wob + WE;      // Q | K | Vt | AO contiguous
  unsigned short* AO  = Qb + 3 * NE;
  unsigned short* mb16 = xb;           // aliases x|kv region (dead after gemm_qkv): 2*NE = CB*CS*CS

  const long TOT = 2 * NE + 4 * WE;
  cvt_all<<<(int)(TOT / 2048), 256, 0, stream>>>(x, kv, WQw, WKw, WVw, WOw, xb);

  gemm_qkv<<<dim3(32, 24), 256, 0, stream>>>(xb, kvb, wqb, WQb, WKb, WVb, Qb);

  mk_mbias<<<(int)(((long)CB * CS * CS) / 2048), 256, 0, stream>>>(ab, mask, mb16);

  attn_kernel<<<dim3(CH, CS / 128, CB), 256, 0, stream>>>(
      Qb, Qb + NE, Qb + 2 * NE, mb16, mask, AO);

  gemm_wo<<<dim3(32, 8), 256, 0, stream>>>(AO, wob, WOb, out);
}

// Round 13
// 149.857 us; speedup vs baseline: 1.0027x; 1.0027x over previous
//
#include <hip/hip_runtime.h>

#define DEV static __device__ __forceinline__

typedef __attribute__((ext_vector_type(8))) __bf16 bf16x8;
typedef __attribute__((ext_vector_type(4))) float f32x4;

constexpr int CB = 2;     // batch
constexpr int CS = 2048;  // seq
constexpr int CE = 1024;  // embed
constexpr int CH = 16;    // heads
constexpr int CD = 64;    // head dim
constexpr float LOG2E = 1.44269504f;

DEV unsigned short f2bf(float x) {  // RNE f32 -> bf16 bits
  unsigned int u = __float_as_uint(x);
  u += 0x7fffu + ((u >> 16) & 1u);
  return (unsigned short)(u >> 16);
}

DEV f32x4 mfma32(bf16x8 a, bf16x8 b, f32x4 c) {  // 16x16x32
  return __builtin_amdgcn_mfma_f32_16x16x32_bf16(a, b, c, 0, 0, 0);
}

DEV unsigned int cvtpk(float lo, float hi) {  // pack 2 f32 -> 2 bf16 (RNE)
  unsigned int r;
  asm("v_cvt_pk_bf16_f32 %0, %1, %2" : "=v"(r) : "v"(lo), "v"(hi));
  return r;
}

DEV float exp2r(float x) {  // raw v_exp_f32
#if __has_builtin(__builtin_amdgcn_exp2f)
  return __builtin_amdgcn_exp2f(x);
#else
  float r; asm("v_exp_f32 %0, %1" : "=v"(r) : "v"(x)); return r;
#endif
}

DEV f32x4 unpk(unsigned int a, unsigned int b) {  // 4 packed bf16 -> f32x4
  f32x4 r;
  r[0] = __uint_as_float(a << 16);
  r[1] = __uint_as_float(a & 0xffff0000u);
  r[2] = __uint_as_float(b << 16);
  r[3] = __uint_as_float(b & 0xffff0000u);
  return r;
}

DEV void stage16(const void* g, void* l) {  // async global(16B/lane) -> LDS
  __builtin_amdgcn_global_load_lds(
      (const __attribute__((address_space(1))) unsigned int*)g,
      (__attribute__((address_space(3))) unsigned int*)l, 16, 0, 0);
}

// ------- fused f32 -> bf16 convert: x | kv | WQ | WK | WV | WO -> contiguous ws -------
__global__ __launch_bounds__(256) void cvt_all(const float* __restrict__ x,
                                               const float* __restrict__ kv,
                                               const float* __restrict__ w0,
                                               const float* __restrict__ w1,
                                               const float* __restrict__ w2,
                                               const float* __restrict__ w3,
                                               unsigned short* __restrict__ out) {
  const long NE = (long)CB * CS * CE;
  const long WE = (long)CE * CE;
  long i = ((long)blockIdx.x * 256 + threadIdx.x) * 8;
  const float* src;
  long off = i;
  if (i < NE) {
    src = x;
  } else if (i < 2 * NE) {
    src = kv; off = i - NE;
  } else {
    long j = i - 2 * NE;
    int wi = (int)(j >> 20);
    src = wi == 0 ? w0 : wi == 1 ? w1 : wi == 2 ? w2 : w3;
    off = j & (WE - 1);
  }
  float4 a = *reinterpret_cast<const float4*>(src + off);
  float4 b = *reinterpret_cast<const float4*>(src + off + 4);
  uint4 v;
  v.x = (unsigned int)f2bf(a.x) | ((unsigned int)f2bf(a.y) << 16);
  v.y = (unsigned int)f2bf(a.z) | ((unsigned int)f2bf(a.w) << 16);
  v.z = (unsigned int)f2bf(b.x) | ((unsigned int)f2bf(b.y) << 16);
  v.w = (unsigned int)f2bf(b.z) | ((unsigned int)f2bf(b.w) << 16);
  *reinterpret_cast<uint4*>(out + i) = v;
}

// ------- mbias (bf16, log2 domain):
//   mq==0            -> 0            (q fully masked: uniform row, matches ref)
//   mq!=0 && mk==0   -> -1e9*log2e   (exp2 -> exact 0)
//   else             -> bias*log2e
__global__ __launch_bounds__(256) void mk_mbias(const float* __restrict__ bias,
                                                const int* __restrict__ mask,
                                                unsigned short* __restrict__ mb16) {
  const long idx = ((long)blockIdx.x * 256 + threadIdx.x) * 8;  // over CB*CS*CS
  const int b = (int)(idx >> 22);
  const int q = (int)((idx >> 11) & (CS - 1));
  const int k0 = (int)(idx & (CS - 1));
  const bool mq = mask[b * CS + q] != 0;
  const int4 mk0 = *reinterpret_cast<const int4*>(mask + b * CS + k0);
  const int4 mk1 = *reinterpret_cast<const int4*>(mask + b * CS + k0 + 4);
  const float4 b0 = *reinterpret_cast<const float4*>(bias + idx);
  const float4 b1 = *reinterpret_cast<const float4*>(bias + idx + 4);
  const float NEG = -1e9f * LOG2E;
  float v[8];
  if (mq) {
    v[0] = (mk0.x != 0) ? b0.x * LOG2E : NEG;
    v[1] = (mk0.y != 0) ? b0.y * LOG2E : NEG;
    v[2] = (mk0.z != 0) ? b0.z * LOG2E : NEG;
    v[3] = (mk0.w != 0) ? b0.w * LOG2E : NEG;
    v[4] = (mk1.x != 0) ? b1.x * LOG2E : NEG;
    v[5] = (mk1.y != 0) ? b1.y * LOG2E : NEG;
    v[6] = (mk1.z != 0) ? b1.z * LOG2E : NEG;
    v[7] = (mk1.w != 0) ? b1.w * LOG2E : NEG;
  } else {
#pragma unroll
    for (int j = 0; j < 8; j++) v[j] = 0.f;  // uniform row (qf also zeroed in attn)
  }
  uint4 o;
  o.x = cvtpk(v[0], v[1]); o.y = cvtpk(v[2], v[3]);
  o.z = cvtpk(v[4], v[5]); o.w = cvtpk(v[6], v[7]);
  *reinterpret_cast<uint4*>(mb16 + idx) = o;
}

// ---------------- fused QKV GEMM: [Q|K|V] = A @ W{q,k,v}^T + bias ----------------
__global__ __launch_bounds__(256) void gemm_qkv(const unsigned short* __restrict__ xb,
                                                const unsigned short* __restrict__ kvb,
                                                const unsigned short* __restrict__ Wall,
                                                const float* __restrict__ bq,
                                                const float* __restrict__ bk,
                                                const float* __restrict__ bv,
                                                unsigned short* __restrict__ Qb) {
  __shared__ __align__(16) unsigned short As[128 * 64];
  __shared__ __align__(16) unsigned short Bs[128 * 64];
  const long NE = (long)CB * CS * CE;
  const long WE = (long)CE * CE;
  const int which = blockIdx.y >> 3;           // 0=Q 1=K 2=V
  const int n0 = (blockIdx.y & 7) * 128;
  const unsigned short* A = which == 0 ? xb : kvb;
  const unsigned short* W = Wall + (long)which * WE;
  const float* bias = which == 0 ? bq : which == 1 ? bk : bv;
  const int tid = threadIdx.x;
  const int lane = tid & 63, wave = tid >> 6;
  const int wm = (wave >> 1) * 64, wn = (wave & 1) * 64;
  const int g = lane >> 4, rr = lane & 15;
  const int m0 = blockIdx.x * 128;
  const int K = CE;
  f32x4 acc[4][4] = {};

  for (int k0 = 0; k0 < K; k0 += 64) {
#pragma unroll
    for (int t = 0; t < 4; t++) {
      const int u = t * 256 + tid;
      const int row = u >> 3, ce = (u & 7) * 8;
      const int lb = (t * 256 + (tid & 192)) * 16;
      stage16(A + (long)(m0 + row) * K + k0 + ce, (char*)As + lb);
      stage16(W + (long)(n0 + row) * K + k0 + ce, (char*)Bs + lb);
    }
    __syncthreads();
#pragma unroll
    for (int kk = 0; kk < 2; kk++) {
      bf16x8 af[4], bfr[4];
#pragma unroll
      for (int i = 0; i < 4; i++)
        af[i] = *reinterpret_cast<const bf16x8*>(&As[(wm + i * 16 + rr) * 64 + kk * 32 + g * 8]);
#pragma unroll
      for (int j = 0; j < 4; j++)
        bfr[j] = *reinterpret_cast<const bf16x8*>(&Bs[(wn + j * 16 + rr) * 64 + kk * 32 + g * 8]);
#pragma unroll
      for (int i = 0; i < 4; i++)
#pragma unroll
        for (int j = 0; j < 4; j++)
          acc[i][j] = mfma32(af[i], bfr[j], acc[i][j]);
    }
    __syncthreads();
  }

  const float scale = which == 0 ? 0.125f * LOG2E : 1.0f;  // fold 1/sqrt(dk)*log2e into Q
#pragma unroll
  for (int i = 0; i < 4; i++) {
#pragma unroll
    for (int j = 0; j < 4; j++) {
      const int colg = n0 + wn + j * 16 + rr;
      const float bvv = bias[colg];
      if (which == 2) {  // V^T layout [B,H,DK,S]
        const int rowbase = m0 + wm + i * 16 + g * 4;
        const int bb = rowbase >> 11, s = rowbase & 2047;
        const int hh = colg >> 6, d = colg & 63;
        uint2 val;
        val.x = (unsigned int)f2bf(acc[i][j][0] + bvv) | ((unsigned int)f2bf(acc[i][j][1] + bvv) << 16);
        val.y = (unsigned int)f2bf(acc[i][j][2] + bvv) | ((unsigned int)f2bf(acc[i][j][3] + bvv) << 16);
        *reinterpret_cast<uint2*>(Qb + 2 * NE + ((long)((bb * CH + hh) * CD + d)) * CS + s) = val;
      } else {
        unsigned short* outp = Qb + (long)which * NE;
#pragma unroll
        for (int r = 0; r < 4; r++) {
          const int row = m0 + wm + i * 16 + g * 4 + r;
          outp[(long)row * CE + colg] = f2bf((acc[i][j][r] + bvv) * scale);
        }
      }
    }
  }
}

// ---------------- WO GEMM: out_f32 = A @ W^T + bias ----------------
__global__ __launch_bounds__(256) void gemm_wo(const unsigned short* __restrict__ A,
                                               const unsigned short* __restrict__ W,
                                               const float* __restrict__ bias,
                                               float* __restrict__ out) {
  __shared__ __align__(16) unsigned short As[128 * 64];
  __shared__ __align__(16) unsigned short Bs[128 * 64];
  const int tid = threadIdx.x;
  const int lane = tid & 63, wave = tid >> 6;
  const int wm = (wave >> 1) * 64, wn = (wave & 1) * 64;
  const int g = lane >> 4, rr = lane & 15;
  const int m0 = blockIdx.x * 128, n0 = blockIdx.y * 128;
  const int K = CE;
  f32x4 acc[4][4] = {};

  for (int k0 = 0; k0 < K; k0 += 64) {
#pragma unroll
    for (int t = 0; t < 4; t++) {
      const int u = t * 256 + tid;
      const int row = u >> 3, ce = (u & 7) * 8;
      const int lb = (t * 256 + (tid & 192)) * 16;
      stage16(A + (long)(m0 + row) * K + k0 + ce, (char*)As + lb);
      stage16(W + (long)(n0 + row) * K + k0 + ce, (char*)Bs + lb);
    }
    __syncthreads();
#pragma unroll
    for (int kk = 0; kk < 2; kk++) {
      bf16x8 af[4], bfr[4];
#pragma unroll
      for (int i = 0; i < 4; i++)
        af[i] = *reinterpret_cast<const bf16x8*>(&As[(wm + i * 16 + rr) * 64 + kk * 32 + g * 8]);
#pragma unroll
      for (int j = 0; j < 4; j++)
        bfr[j] = *reinterpret_cast<const bf16x8*>(&Bs[(wn + j * 16 + rr) * 64 + kk * 32 + g * 8]);
#pragma unroll
      for (int i = 0; i < 4; i++)
#pragma unroll
        for (int j = 0; j < 4; j++)
          acc[i][j] = mfma32(af[i], bfr[j], acc[i][j]);
    }
    __syncthreads();
  }

#pragma unroll
  for (int i = 0; i < 4; i++)
#pragma unroll
    for (int j = 0; j < 4; j++) {
      const int colg = n0 + wn + j * 16 + rr;
      const float bvv = bias[colg];
#pragma unroll
      for (int r = 0; r < 4; r++) {
        const int row = m0 + wm + i * 16 + g * 4 + r;
        out[(long)row * CE + colg] = acc[i][j][r] + bvv;
      }
    }
}

// ---------------- Flash attention v12: BK=128 (half the barriers) ----------------
// Grid (h, qt, b) XCD co-location; static softmax; permuted-K LDS; counted vmcnt.
// 128-key tiles: LDS buf = [K 16KB (128 rows x 128B)][V 2x8KB half-tiles (64 d-rows
// x 128B, keys half*64..+63)]; double-buffered = 64KB. Per tile vmem = [mb:8][stage:8]
// -> head wait vmcnt(16). 16 tiles, 2 barriers each (was 32x2).
__global__ __launch_bounds__(256, 2) void attn_kernel(const unsigned short* __restrict__ Qb,
                                                      const unsigned short* __restrict__ Kb,
                                                      const unsigned short* __restrict__ Vtw,
                                                      const unsigned short* __restrict__ mb16,
                                                      const int* __restrict__ mask,
                                                      unsigned short* __restrict__ AO) {
  __shared__ __align__(16) unsigned char lds[65536];
  const int h = blockIdx.x, qt = blockIdx.y, b = blockIdx.z;
  const int tid = threadIdx.x;
  const int lane = tid & 63, w = tid >> 6;
  const int g = lane >> 4, c = lane & 15;
  const int qbase = qt * 128 + w * 32;  // + qb*16 + c

  bf16x8 qf[2][2];  // [qb][kd]; B-frag col=c=q, k(d)=kd*32+g*8+j (Q pre-scaled 0.125*log2e)
#pragma unroll
  for (int qb = 0; qb < 2; qb++) {
    const unsigned short* Qrow = Qb + ((long)b * CS + qbase + qb * 16 + c) * CE + h * CD;
    qf[qb][0] = *reinterpret_cast<const bf16x8*>(Qrow + g * 8);
    qf[qb][1] = *reinterpret_cast<const bf16x8*>(Qrow + 32 + g * 8);
    if (mask[b * CS + qbase + qb * 16 + c] == 0) {  // uniform masked rows (mbias=0 there)
      qf[qb][0] = bf16x8{}; qf[qb][1] = bf16x8{};
    }
  }

  // stage sources (per-lane), induction-advanced per 128-key tile
  const unsigned char *kg[4], *vg[4];
  {
    const unsigned char* Ksrc = (const unsigned char*)(Kb + (long)b * CS * CE + h * CD);
    const unsigned char* Vsrc = (const unsigned char*)(Vtw + (long)(b * CH + h) * CD * CS);
    const int rr8 = lane >> 3;                    // 0..7
    const int csw = ((lane & 7) << 4) ^ (rr8 << 4);  // inverse-swizzled source col
#pragma unroll
    for (int t = 0; t < 4; t++) {
      const int krow = t * 32 + w * 8 + rr8;      // LDS K row 0..127
      // LDS row -> key permutation (PV B-frag order), extended to 128 rows
      const int key = (krow & 96) + ((krow >> 2) & 3) * 8 + ((krow >> 4) & 1) * 4 + (krow & 3);
      kg[t] = Ksrc + (long)key * (CE * 2) + csw;
      const int vrow = (t & 1) * 32 + w * 8 + rr8;  // d-row within half-tile
      vg[t] = Vsrc + (long)vrow * (CS * 2) + (t >> 1) * 128 + csw;  // half offset = 64 keys *2B
    }
  }
  // LDS read bases (per-lane); all reads = base + compile-time immediate
  const int sw = (c & 7) << 4;
  const unsigned char* rb0 = lds + c * 128 + ((g * 16) ^ sw);
  const unsigned char* rb1 = lds + c * 128 + ((64 + g * 16) ^ sw);

  // mbias running pointers per qb (+128 elements per real tile)
  const unsigned short* mbp0 = mb16 + ((long)b * CS + qbase + c) * CS + g * 8;
  const unsigned short* mbp1 = mb16 + ((long)b * CS + qbase + 16 + c) * CS + g * 8;

  f32x4 o[2][4] = {};
  f32x4 lsum4[2] = {};
  uint4 mbr[2][4];  // [qb][kb] 8 bf16 each: k = kb*32 + g*8 + j

  auto stage = [&](int bo) {  // 8 vmem ops; advances to next tile
    unsigned char* kbuf = lds + bo;
    unsigned char* vbuf = lds + bo + 16384;
#pragma unroll
    for (int t = 0; t < 4; t++) {
      stage16(kg[t], kbuf + t * 4096 + w * 1024);
      stage16(vg[t], vbuf + (t >> 1) * 8192 + (t & 1) * 4096 + w * 1024);
      kg[t] += 128 * CE * 2;
      vg[t] += 128 * 2;
    }
  };
  auto load_mb = [&](bool adv) {  // 8 vmem ops (16B each)
#pragma unroll
    for (int kb = 0; kb < 4; kb++) {
      mbr[0][kb] = *reinterpret_cast<const uint4*>(mbp0 + kb * 32);
      mbr[1][kb] = *reinterpret_cast<const uint4*>(mbp1 + kb * 32);
    }
    if (adv) { mbp0 += 128; mbp1 += 128; }
  };

  auto compute = [&](int bo, bool adv) {
    // ---- S^T: C-init = mbias (bf16 unpack), += K @ Q^T ----
    f32x4 sf[2][8];
    __builtin_amdgcn_s_setprio(1);
#pragma unroll
    for (int cb = 0; cb < 8; cb++) {
      const bf16x8 kf0 = *reinterpret_cast<const bf16x8*>(rb0 + bo + cb * 2048);
      const bf16x8 kf1 = *reinterpret_cast<const bf16x8*>(rb1 + bo + cb * 2048);
#pragma unroll
      for (int qb = 0; qb < 2; qb++) {
        const uint4 m = mbr[qb][cb >> 1];
        const f32x4 ci = (cb & 1) ? unpk(m.z, m.w) : unpk(m.x, m.y);
        f32x4 t = mfma32(kf0, qf[qb][0], ci);
        sf[qb][cb] = mfma32(kf1, qf[qb][1], t);
      }
    }
    __builtin_amdgcn_s_setprio(0);
    load_mb(adv);  // prefetch next tile's mbias (8 vmem)
    // ---- STATIC softmax: p = exp2(sf) straight through ----
    uint4 pw[2][4];
#pragma unroll
    for (int qb = 0; qb < 2; qb++)
#pragma unroll
      for (int kb = 0; kb < 4; kb++)
#pragma unroll
        for (int half = 0; half < 2; half++) {
          const int cb = 2 * kb + half;
          f32x4 pv;
          pv[0] = exp2r(sf[qb][cb][0]);
          pv[1] = exp2r(sf[qb][cb][1]);
          pv[2] = exp2r(sf[qb][cb][2]);
          pv[3] = exp2r(sf[qb][cb][3]);
          lsum4[qb] = lsum4[qb] + pv;
          if (half == 0) { pw[qb][kb].x = cvtpk(pv[0], pv[1]); pw[qb][kb].y = cvtpk(pv[2], pv[3]); }
          else           { pw[qb][kb].z = cvtpk(pv[0], pv[1]); pw[qb][kb].w = cvtpk(pv[2], pv[3]); }
        }
    // ---- O^T += V^T P^T (V frags shared across qb) ----
    __builtin_amdgcn_s_setprio(1);
#pragma unroll
    for (int nb = 0; nb < 4; nb++) {
#pragma unroll
      for (int kb = 0; kb < 4; kb++) {
        const unsigned char* rbx = (kb & 1) ? rb1 : rb0;
        const bf16x8 vf = *reinterpret_cast<const bf16x8*>(
            rbx + bo + 16384 + (kb >> 1) * 8192 + nb * 2048);
#pragma unroll
        for (int qb = 0; qb < 2; qb++)
          o[qb][nb] = mfma32(vf, __builtin_bit_cast(bf16x8, pw[qb][kb]), o[qb][nb]);
      }
    }
    __builtin_amdgcn_s_setprio(0);
  };

  stage(0);         // tile 0 -> buf0  [8]
  load_mb(true);    // mb = tile 0     [8]
  stage(32768);     // tile 1 -> buf1  [8]

#pragma unroll 1
  for (int it = 0; it < 8; ++it) {  // 16 tiles of 128 keys
    // ---- tile t=2it (buf0) ----
    asm volatile("s_waitcnt vmcnt(16)" ::: "memory");  // retire stage(t); mb(t)+stage(t+1) stay
    __builtin_amdgcn_s_barrier();
    __builtin_amdgcn_sched_barrier(0);
    compute(0, it < 7);                                // loads mb(t+1) inside
    __builtin_amdgcn_sched_barrier(0);
    __builtin_amdgcn_s_barrier();
    stage(0);                                          // tile t+2 (junk at tail, valid mem)
    // ---- tile t+1 (buf1) ----
    asm volatile("s_waitcnt vmcnt(16)" ::: "memory");
    __builtin_amdgcn_s_barrier();
    __builtin_amdgcn_sched_barrier(0);
    compute(32768, it < 7);                            // loads mb(t+2) inside (junk at tail)
    __builtin_amdgcn_sched_barrier(0);
    __builtin_amdgcn_s_barrier();
    stage(32768);                                      // tile t+3 (junk at tail, valid mem)
  }

#pragma unroll
  for (int qb = 0; qb < 2; qb++) {
    float lsum = (lsum4[qb][0] + lsum4[qb][1]) + (lsum4[qb][2] + lsum4[qb][3]);
    lsum += __shfl_xor(lsum, 16, 64);
    lsum += __shfl_xor(lsum, 32, 64);
    const float linv = 1.0f / lsum;
    unsigned short* Orow = AO + ((long)b * CS + qbase + qb * 16 + c) * CE + h * CD;
#pragma unroll
    for (int nb = 0; nb < 4; nb++) {
      uint2 val;
      val.x = (unsigned int)f2bf(o[qb][nb][0] * linv) | ((unsigned int)f2bf(o[qb][nb][1] * linv) << 16);
      val.y = (unsigned int)f2bf(o[qb][nb][2] * linv) | ((unsigned int)f2bf(o[qb][nb][3] * linv) << 16);
      *reinterpret_cast<uint2*>(Orow + nb * 16 + g * 4) = val;
    }
  }
  asm volatile("s_waitcnt vmcnt(0)" ::: "memory");  // drain junk stages before endpgm
}

// ---------------- host ----------------
extern "C" void kernel_launch(void* const* d_in, const int* in_sizes, int n_in,
                              void* d_out, int out_size, void* d_ws, size_t ws_size,
                              hipStream_t stream) {
  (void)in_sizes; (void)n_in; (void)out_size; (void)ws_size;
  const float* x    = (const float*)d_in[0];
  const float* kv   = (const float*)d_in[1];
  const int*   mask = (const int*)d_in[2];
  const float* ab   = (const float*)d_in[3];
  const float* WQw  = (const float*)d_in[4];
  const float* WQb  = (const float*)d_in[5];
  const float* WKw  = (const float*)d_in[6];
  const float* WKb  = (const float*)d_in[7];
  const float* WVw  = (const float*)d_in[8];
  const float* WVb  = (const float*)d_in[9];
  const float* WOw  = (const float*)d_in[10];
  const float* WOb  = (const float*)d_in[11];
  float* out = (float*)d_out;

  const long NE = (long)CB * CS * CE;  // 4,194,304
  const long WE = (long)CE * CE;       // 1,048,576
  unsigned short* ws  = (unsigned short*)d_ws;
  unsigned short* xb  = ws;            // [x | kv | WQ | WK | WV | WO] contiguous
  unsigned short* kvb = xb + NE;
  unsigned short* wqb = kvb + NE;      // WQ|WK|WV contiguous = Wall
  unsigned short* wob = wqb + 3 * WE;
  unsigned short* Qb  = wob + WE;      // Q | K | Vt | AO contiguous
  unsigned short* AO  = Qb + 3 * NE;
  unsigned short* mb16 = xb;           // aliases x|kv region (dead after gemm_qkv): 2*NE = CB*CS*CS

  const long TOT = 2 * NE + 4 * WE;
  cvt_all<<<(int)(TOT / 2048), 256, 0, stream>>>(x, kv, WQw, WKw, WVw, WOw, xb);

  gemm_qkv<<<dim3(32, 24), 256, 0, stream>>>(xb, kvb, wqb, WQb, WKb, WVb, Qb);

  mk_mbias<<<(int)(((long)CB * CS * CS) / 2048), 256, 0, stream>>>(ab, mask, mb16);

  attn_kernel<<<dim3(CH, CS / 128, CB), 256, 0, stream>>>(
      Qb, Qb + NE, Qb + 2 * NE, mb16, mask, AO);

  gemm_wo<<<dim3(32, 8), 256, 0, stream>>>(AO, wob, WOb, out);
}

// Round 14
// 143.069 us; speedup vs baseline: 1.0503x; 1.0474x over previous
//
#include <hip/hip_runtime.h>

#define DEV static __device__ __forceinline__

typedef __attribute__((ext_vector_type(8))) __bf16 bf16x8;
typedef __attribute__((ext_vector_type(4))) float f32x4;

constexpr int CB = 2;     // batch
constexpr int CS = 2048;  // seq
constexpr int CE = 1024;  // embed
constexpr int CH = 16;    // heads
constexpr int CD = 64;    // head dim
constexpr float LOG2E = 1.44269504f;

DEV unsigned short f2bf(float x) {  // RNE f32 -> bf16 bits
  unsigned int u = __float_as_uint(x);
  u += 0x7fffu + ((u >> 16) & 1u);
  return (unsigned short)(u >> 16);
}

DEV f32x4 mfma32(bf16x8 a, bf16x8 b, f32x4 c) {  // 16x16x32
  return __builtin_amdgcn_mfma_f32_16x16x32_bf16(a, b, c, 0, 0, 0);
}

DEV unsigned int cvtpk(float lo, float hi) {  // pack 2 f32 -> 2 bf16 (RNE)
  unsigned int r;
  asm("v_cvt_pk_bf16_f32 %0, %1, %2" : "=v"(r) : "v"(lo), "v"(hi));
  return r;
}

DEV float exp2r(float x) {  // raw v_exp_f32
#if __has_builtin(__builtin_amdgcn_exp2f)
  return __builtin_amdgcn_exp2f(x);
#else
  float r; asm("v_exp_f32 %0, %1" : "=v"(r) : "v"(x)); return r;
#endif
}

DEV f32x4 unpk(unsigned int a, unsigned int b) {  // 4 packed bf16 -> f32x4
  f32x4 r;
  r[0] = __uint_as_float(a << 16);
  r[1] = __uint_as_float(a & 0xffff0000u);
  r[2] = __uint_as_float(b << 16);
  r[3] = __uint_as_float(b & 0xffff0000u);
  return r;
}

DEV void stage16(const void* g, void* l) {  // async global(16B/lane) -> LDS
  __builtin_amdgcn_global_load_lds(
      (const __attribute__((address_space(1))) unsigned int*)g,
      (__attribute__((address_space(3))) unsigned int*)l, 16, 0, 0);
}

// ---- elementwise bodies (shared by fused and fallback paths) ----
DEV void cvt_body(long i, const float* __restrict__ x, const float* __restrict__ kv,
                  const float* __restrict__ w0, const float* __restrict__ w1,
                  const float* __restrict__ w2, const float* __restrict__ w3,
                  unsigned short* __restrict__ out) {
  const long NE = (long)CB * CS * CE;
  const long WE = (long)CE * CE;
  const float* src;
  long off = i;
  if (i < NE) {
    src = x;
  } else if (i < 2 * NE) {
    src = kv; off = i - NE;
  } else {
    long j = i - 2 * NE;
    int wi = (int)(j >> 20);
    src = wi == 0 ? w0 : wi == 1 ? w1 : wi == 2 ? w2 : w3;
    off = j & (WE - 1);
  }
  float4 a = *reinterpret_cast<const float4*>(src + off);
  float4 b = *reinterpret_cast<const float4*>(src + off + 4);
  uint4 v;
  v.x = (unsigned int)f2bf(a.x) | ((unsigned int)f2bf(a.y) << 16);
  v.y = (unsigned int)f2bf(a.z) | ((unsigned int)f2bf(a.w) << 16);
  v.z = (unsigned int)f2bf(b.x) | ((unsigned int)f2bf(b.y) << 16);
  v.w = (unsigned int)f2bf(b.z) | ((unsigned int)f2bf(b.w) << 16);
  *reinterpret_cast<uint4*>(out + i) = v;
}

// mbias (bf16, log2 domain): mq==0 -> 0 ; mq&&mk==0 -> -1e9*log2e ; else bias*log2e
DEV void mbias_body(long idx, const float* __restrict__ bias, const int* __restrict__ mask,
                    unsigned short* __restrict__ mb16) {
  const int b = (int)(idx >> 22);
  const int q = (int)((idx >> 11) & (CS - 1));
  const int k0 = (int)(idx & (CS - 1));
  const bool mq = mask[b * CS + q] != 0;
  const int4 mk0 = *reinterpret_cast<const int4*>(mask + b * CS + k0);
  const int4 mk1 = *reinterpret_cast<const int4*>(mask + b * CS + k0 + 4);
  const float4 b0 = *reinterpret_cast<const float4*>(bias + idx);
  const float4 b1 = *reinterpret_cast<const float4*>(bias + idx + 4);
  const float NEG = -1e9f * LOG2E;
  float v[8];
  if (mq) {
    v[0] = (mk0.x != 0) ? b0.x * LOG2E : NEG;
    v[1] = (mk0.y != 0) ? b0.y * LOG2E : NEG;
    v[2] = (mk0.z != 0) ? b0.z * LOG2E : NEG;
    v[3] = (mk0.w != 0) ? b0.w * LOG2E : NEG;
    v[4] = (mk1.x != 0) ? b1.x * LOG2E : NEG;
    v[5] = (mk1.y != 0) ? b1.y * LOG2E : NEG;
    v[6] = (mk1.z != 0) ? b1.z * LOG2E : NEG;
    v[7] = (mk1.w != 0) ? b1.w * LOG2E : NEG;
  } else {
#pragma unroll
    for (int j = 0; j < 8; j++) v[j] = 0.f;  // uniform row (qf also zeroed in attn)
  }
  uint4 o;
  o.x = cvtpk(v[0], v[1]); o.y = cvtpk(v[2], v[3]);
  o.z = cvtpk(v[4], v[5]); o.w = cvtpk(v[6], v[7]);
  *reinterpret_cast<uint4*>(mb16 + idx) = o;
}

// ------- fused prep: cvt blocks then mbias blocks (mb16 must NOT alias cvt dst) -------
__global__ __launch_bounds__(256) void prep_all(const float* __restrict__ x,
                                                const float* __restrict__ kv,
                                                const float* __restrict__ w0,
                                                const float* __restrict__ w1,
                                                const float* __restrict__ w2,
                                                const float* __restrict__ w3,
                                                unsigned short* __restrict__ outcvt,
                                                const float* __restrict__ bias,
                                                const int* __restrict__ mask,
                                                unsigned short* __restrict__ mb16) {
  const long CVTB = (2 * (long)CB * CS * CE + 4 * (long)CE * CE) / 2048;  // 6144
  if (blockIdx.x < CVTB) {
    cvt_body(((long)blockIdx.x * 256 + threadIdx.x) * 8, x, kv, w0, w1, w2, w3, outcvt);
  } else {
    mbias_body(((long)(blockIdx.x - CVTB) * 256 + threadIdx.x) * 8, bias, mask, mb16);
  }
}

// ------- fallback split kernels (used when ws too small for fused layout) -------
__global__ __launch_bounds__(256) void cvt_all(const float* __restrict__ x,
                                               const float* __restrict__ kv,
                                               const float* __restrict__ w0,
                                               const float* __restrict__ w1,
                                               const float* __restrict__ w2,
                                               const float* __restrict__ w3,
                                               unsigned short* __restrict__ out) {
  cvt_body(((long)blockIdx.x * 256 + threadIdx.x) * 8, x, kv, w0, w1, w2, w3, out);
}
__global__ __launch_bounds__(256) void mk_mbias(const float* __restrict__ bias,
                                                const int* __restrict__ mask,
                                                unsigned short* __restrict__ mb16) {
  mbias_body(((long)blockIdx.x * 256 + threadIdx.x) * 8, bias, mask, mb16);
}

// ---------------- fused QKV GEMM: [Q|K|V] = A @ W{q,k,v}^T + bias ----------------
__global__ __launch_bounds__(256) void gemm_qkv(const unsigned short* __restrict__ xb,
                                                const unsigned short* __restrict__ kvb,
                                                const unsigned short* __restrict__ Wall,
                                                const float* __restrict__ bq,
                                                const float* __restrict__ bk,
                                                const float* __restrict__ bv,
                                                unsigned short* __restrict__ Qb) {
  __shared__ __align__(16) unsigned short As[128 * 64];
  __shared__ __align__(16) unsigned short Bs[128 * 64];
  const long NE = (long)CB * CS * CE;
  const long WE = (long)CE * CE;
  const int which = blockIdx.y >> 3;           // 0=Q 1=K 2=V
  const int n0 = (blockIdx.y & 7) * 128;
  const unsigned short* A = which == 0 ? xb : kvb;
  const unsigned short* W = Wall + (long)which * WE;
  const float* bias = which == 0 ? bq : which == 1 ? bk : bv;
  const int tid = threadIdx.x;
  const int lane = tid & 63, wave = tid >> 6;
  const int wm = (wave >> 1) * 64, wn = (wave & 1) * 64;
  const int g = lane >> 4, rr = lane & 15;
  const int m0 = blockIdx.x * 128;
  const int K = CE;
  f32x4 acc[4][4] = {};

  for (int k0 = 0; k0 < K; k0 += 64) {
#pragma unroll
    for (int t = 0; t < 4; t++) {
      const int u = t * 256 + tid;
      const int row = u >> 3, ce = (u & 7) * 8;
      const int lb = (t * 256 + (tid & 192)) * 16;
      stage16(A + (long)(m0 + row) * K + k0 + ce, (char*)As + lb);
      stage16(W + (long)(n0 + row) * K + k0 + ce, (char*)Bs + lb);
    }
    __syncthreads();
#pragma unroll
    for (int kk = 0; kk < 2; kk++) {
      bf16x8 af[4], bfr[4];
#pragma unroll
      for (int i = 0; i < 4; i++)
        af[i] = *reinterpret_cast<const bf16x8*>(&As[(wm + i * 16 + rr) * 64 + kk * 32 + g * 8]);
#pragma unroll
      for (int j = 0; j < 4; j++)
        bfr[j] = *reinterpret_cast<const bf16x8*>(&Bs[(wn + j * 16 + rr) * 64 + kk * 32 + g * 8]);
#pragma unroll
      for (int i = 0; i < 4; i++)
#pragma unroll
        for (int j = 0; j < 4; j++)
          acc[i][j] = mfma32(af[i], bfr[j], acc[i][j]);
    }
    __syncthreads();
  }

  const float scale = which == 0 ? 0.125f * LOG2E : 1.0f;  // fold 1/sqrt(dk)*log2e into Q
#pragma unroll
  for (int i = 0; i < 4; i++) {
#pragma unroll
    for (int j = 0; j < 4; j++) {
      const int colg = n0 + wn + j * 16 + rr;
      const float bvv = bias[colg];
      if (which == 2) {  // V^T layout [B,H,DK,S]
        const int rowbase = m0 + wm + i * 16 + g * 4;
        const int bb = rowbase >> 11, s = rowbase & 2047;
        const int hh = colg >> 6, d = colg & 63;
        uint2 val;
        val.x = (unsigned int)f2bf(acc[i][j][0] + bvv) | ((unsigned int)f2bf(acc[i][j][1] + bvv) << 16);
        val.y = (unsigned int)f2bf(acc[i][j][2] + bvv) | ((unsigned int)f2bf(acc[i][j][3] + bvv) << 16);
        *reinterpret_cast<uint2*>(Qb + 2 * NE + ((long)((bb * CH + hh) * CD + d)) * CS + s) = val;
      } else {
        unsigned short* outp = Qb + (long)which * NE;
#pragma unroll
        for (int r = 0; r < 4; r++) {
          const int row = m0 + wm + i * 16 + g * 4 + r;
          outp[(long)row * CE + colg] = f2bf((acc[i][j][r] + bvv) * scale);
        }
      }
    }
  }
}

// ---------------- WO GEMM v2: 128x64 tile, 512 blocks (2/CU) ----------------
__global__ __launch_bounds__(256) void gemm_wo(const unsigned short* __restrict__ A,
                                               const unsigned short* __restrict__ W,
                                               const float* __restrict__ bias,
                                               float* __restrict__ out) {
  __shared__ __align__(16) unsigned short As[128 * 64];  // 16 KB
  __shared__ __align__(16) unsigned short Bs[64 * 64];   // 8 KB
  const int tid = threadIdx.x;
  const int lane = tid & 63, wave = tid >> 6;
  const int wm = (wave >> 1) * 64, wn = (wave & 1) * 32;
  const int g = lane >> 4, rr = lane & 15;
  const int m0 = blockIdx.x * 128, n0 = blockIdx.y * 64;
  const int K = CE;
  f32x4 acc[4][2] = {};

  for (int k0 = 0; k0 < K; k0 += 64) {
#pragma unroll
    for (int t = 0; t < 4; t++) {
      const int u = t * 256 + tid;
      const int row = u >> 3, ce = (u & 7) * 8;
      stage16(A + (long)(m0 + row) * K + k0 + ce, (char*)As + (t * 256 + (tid & 192)) * 16);
    }
#pragma unroll
    for (int t = 0; t < 2; t++) {
      const int u = t * 256 + tid;
      const int row = u >> 3, ce = (u & 7) * 8;
      stage16(W + (long)(n0 + row) * K + k0 + ce, (char*)Bs + (t * 256 + (tid & 192)) * 16);
    }
    __syncthreads();
#pragma unroll
    for (int kk = 0; kk < 2; kk++) {
      bf16x8 af[4], bfr[2];
#pragma unroll
      for (int i = 0; i < 4; i++)
        af[i] = *reinterpret_cast<const bf16x8*>(&As[(wm + i * 16 + rr) * 64 + kk * 32 + g * 8]);
#pragma unroll
      for (int j = 0; j < 2; j++)
        bfr[j] = *reinterpret_cast<const bf16x8*>(&Bs[(wn + j * 16 + rr) * 64 + kk * 32 + g * 8]);
#pragma unroll
      for (int i = 0; i < 4; i++)
#pragma unroll
        for (int j = 0; j < 2; j++)
          acc[i][j] = mfma32(af[i], bfr[j], acc[i][j]);
    }
    __syncthreads();
  }

#pragma unroll
  for (int i = 0; i < 4; i++)
#pragma unroll
    for (int j = 0; j < 2; j++) {
      const int colg = n0 + wn + j * 16 + rr;
      const float bvv = bias[colg];
#pragma unroll
      for (int r = 0; r < 4; r++) {
        const int row = m0 + wm + i * 16 + g * 4 + r;
        out[(long)row * CE + colg] = acc[i][j][r] + bvv;
      }
    }
}

// ---------------- Flash attention v12: BK=128, static softmax (unchanged) ----------------
__global__ __launch_bounds__(256, 2) void attn_kernel(const unsigned short* __restrict__ Qb,
                                                      const unsigned short* __restrict__ Kb,
                                                      const unsigned short* __restrict__ Vtw,
                                                      const unsigned short* __restrict__ mb16,
                                                      const int* __restrict__ mask,
                                                      unsigned short* __restrict__ AO) {
  __shared__ __align__(16) unsigned char lds[65536];
  const int h = blockIdx.x, qt = blockIdx.y, b = blockIdx.z;
  const int tid = threadIdx.x;
  const int lane = tid & 63, w = tid >> 6;
  const int g = lane >> 4, c = lane & 15;
  const int qbase = qt * 128 + w * 32;  // + qb*16 + c

  bf16x8 qf[2][2];  // [qb][kd]; B-frag col=c=q, k(d)=kd*32+g*8+j (Q pre-scaled 0.125*log2e)
#pragma unroll
  for (int qb = 0; qb < 2; qb++) {
    const unsigned short* Qrow = Qb + ((long)b * CS + qbase + qb * 16 + c) * CE + h * CD;
    qf[qb][0] = *reinterpret_cast<const bf16x8*>(Qrow + g * 8);
    qf[qb][1] = *reinterpret_cast<const bf16x8*>(Qrow + 32 + g * 8);
    if (mask[b * CS + qbase + qb * 16 + c] == 0) {  // uniform masked rows (mbias=0 there)
      qf[qb][0] = bf16x8{}; qf[qb][1] = bf16x8{};
    }
  }

  // stage sources (per-lane), induction-advanced per 128-key tile
  const unsigned char *kg[4], *vg[4];
  {
    const unsigned char* Ksrc = (const unsigned char*)(Kb + (long)b * CS * CE + h * CD);
    const unsigned char* Vsrc = (const unsigned char*)(Vtw + (long)(b * CH + h) * CD * CS);
    const int rr8 = lane >> 3;
    const int csw = ((lane & 7) << 4) ^ (rr8 << 4);
#pragma unroll
    for (int t = 0; t < 4; t++) {
      const int krow = t * 32 + w * 8 + rr8;
      const int key = (krow & 96) + ((krow >> 2) & 3) * 8 + ((krow >> 4) & 1) * 4 + (krow & 3);
      kg[t] = Ksrc + (long)key * (CE * 2) + csw;
      const int vrow = (t & 1) * 32 + w * 8 + rr8;
      vg[t] = Vsrc + (long)vrow * (CS * 2) + (t >> 1) * 128 + csw;
    }
  }
  const int sw = (c & 7) << 4;
  const unsigned char* rb0 = lds + c * 128 + ((g * 16) ^ sw);
  const unsigned char* rb1 = lds + c * 128 + ((64 + g * 16) ^ sw);

  const unsigned short* mbp0 = mb16 + ((long)b * CS + qbase + c) * CS + g * 8;
  const unsigned short* mbp1 = mb16 + ((long)b * CS + qbase + 16 + c) * CS + g * 8;

  f32x4 o[2][4] = {};
  f32x4 lsum4[2] = {};
  uint4 mbr[2][4];

  auto stage = [&](int bo) {  // 8 vmem ops
    unsigned char* kbuf = lds + bo;
    unsigned char* vbuf = lds + bo + 16384;
#pragma unroll
    for (int t = 0; t < 4; t++) {
      stage16(kg[t], kbuf + t * 4096 + w * 1024);
      stage16(vg[t], vbuf + (t >> 1) * 8192 + (t & 1) * 4096 + w * 1024);
      kg[t] += 128 * CE * 2;
      vg[t] += 128 * 2;
    }
  };
  auto load_mb = [&](bool adv) {  // 8 vmem ops
#pragma unroll
    for (int kb = 0; kb < 4; kb++) {
      mbr[0][kb] = *reinterpret_cast<const uint4*>(mbp0 + kb * 32);
      mbr[1][kb] = *reinterpret_cast<const uint4*>(mbp1 + kb * 32);
    }
    if (adv) { mbp0 += 128; mbp1 += 128; }
  };

  auto compute = [&](int bo, bool adv) {
    f32x4 sf[2][8];
    __builtin_amdgcn_s_setprio(1);
#pragma unroll
    for (int cb = 0; cb < 8; cb++) {
      const bf16x8 kf0 = *reinterpret_cast<const bf16x8*>(rb0 + bo + cb * 2048);
      const bf16x8 kf1 = *reinterpret_cast<const bf16x8*>(rb1 + bo + cb * 2048);
#pragma unroll
      for (int qb = 0; qb < 2; qb++) {
        const uint4 m = mbr[qb][cb >> 1];
        const f32x4 ci = (cb & 1) ? unpk(m.z, m.w) : unpk(m.x, m.y);
        f32x4 t = mfma32(kf0, qf[qb][0], ci);
        sf[qb][cb] = mfma32(kf1, qf[qb][1], t);
      }
    }
    __builtin_amdgcn_s_setprio(0);
    load_mb(adv);
    uint4 pw[2][4];
#pragma unroll
    for (int qb = 0; qb < 2; qb++)
#pragma unroll
      for (int kb = 0; kb < 4; kb++)
#pragma unroll
        for (int half = 0; half < 2; half++) {
          const int cb = 2 * kb + half;
          f32x4 pv;
          pv[0] = exp2r(sf[qb][cb][0]);
          pv[1] = exp2r(sf[qb][cb][1]);
          pv[2] = exp2r(sf[qb][cb][2]);
          pv[3] = exp2r(sf[qb][cb][3]);
          lsum4[qb] = lsum4[qb] + pv;
          if (half == 0) { pw[qb][kb].x = cvtpk(pv[0], pv[1]); pw[qb][kb].y = cvtpk(pv[2], pv[3]); }
          else           { pw[qb][kb].z = cvtpk(pv[0], pv[1]); pw[qb][kb].w = cvtpk(pv[2], pv[3]); }
        }
    __builtin_amdgcn_s_setprio(1);
#pragma unroll
    for (int nb = 0; nb < 4; nb++) {
#pragma unroll
      for (int kb = 0; kb < 4; kb++) {
        const unsigned char* rbx = (kb & 1) ? rb1 : rb0;
        const bf16x8 vf = *reinterpret_cast<const bf16x8*>(
            rbx + bo + 16384 + (kb >> 1) * 8192 + nb * 2048);
#pragma unroll
        for (int qb = 0; qb < 2; qb++)
          o[qb][nb] = mfma32(vf, __builtin_bit_cast(bf16x8, pw[qb][kb]), o[qb][nb]);
      }
    }
    __builtin_amdgcn_s_setprio(0);
  };

  stage(0);
  load_mb(true);
  stage(32768);

#pragma unroll 1
  for (int it = 0; it < 8; ++it) {  // 16 tiles of 128 keys
    asm volatile("s_waitcnt vmcnt(16)" ::: "memory");
    __builtin_amdgcn_s_barrier();
    __builtin_amdgcn_sched_barrier(0);
    compute(0, it < 7);
    __builtin_amdgcn_sched_barrier(0);
    __builtin_amdgcn_s_barrier();
    stage(0);
    asm volatile("s_waitcnt vmcnt(16)" ::: "memory");
    __builtin_amdgcn_s_barrier();
    __builtin_amdgcn_sched_barrier(0);
    compute(32768, it < 7);
    __builtin_amdgcn_sched_barrier(0);
    __builtin_amdgcn_s_barrier();
    stage(32768);
  }

#pragma unroll
  for (int qb = 0; qb < 2; qb++) {
    float lsum = (lsum4[qb][0] + lsum4[qb][1]) + (lsum4[qb][2] + lsum4[qb][3]);
    lsum += __shfl_xor(lsum, 16, 64);
    lsum += __shfl_xor(lsum, 32, 64);
    const float linv = 1.0f / lsum;
    unsigned short* Orow = AO + ((long)b * CS + qbase + qb * 16 + c) * CE + h * CD;
#pragma unroll
    for (int nb = 0; nb < 4; nb++) {
      uint2 val;
      val.x = (unsigned int)f2bf(o[qb][nb][0] * linv) | ((unsigned int)f2bf(o[qb][nb][1] * linv) << 16);
      val.y = (unsigned int)f2bf(o[qb][nb][2] * linv) | ((unsigned int)f2bf(o[qb][nb][3] * linv) << 16);
      *reinterpret_cast<uint2*>(Orow + nb * 16 + g * 4) = val;
    }
  }
  asm volatile("s_waitcnt vmcnt(0)" ::: "memory");  // drain junk stages before endpgm
}

// ---------------- host ----------------
extern "C" void kernel_launch(void* const* d_in, const int* in_sizes, int n_in,
                              void* d_out, int out_size, void* d_ws, size_t ws_size,
                              hipStream_t stream) {
  (void)in_sizes; (void)n_in; (void)out_size;
  const float* x    = (const float*)d_in[0];
  const float* kv   = (const float*)d_in[1];
  const int*   mask = (const int*)d_in[2];
  const float* ab   = (const float*)d_in[3];
  const float* WQw  = (const float*)d_in[4];
  const float* WQb  = (const float*)d_in[5];
  const float* WKw  = (const float*)d_in[6];
  const float* WKb  = (const float*)d_in[7];
  const float* WVw  = (const float*)d_in[8];
  const float* WVb  = (const float*)d_in[9];
  const float* WOw  = (const float*)d_in[10];
  const float* WOb  = (const float*)d_in[11];
  float* out = (float*)d_out;

  const long NE = (long)CB * CS * CE;  // 4,194,304
  const long WE = (long)CE * CE;       // 1,048,576
  unsigned short* ws  = (unsigned short*)d_ws;
  unsigned short* xb  = ws;            // [x | kv | WQ | WK | WV | WO] contiguous
  unsigned short* kvb = xb + NE;
  unsigned short* wqb = kvb + NE;      // WQ|WK|WV contiguous = Wall
  unsigned short* wob = wqb + 3 * WE;
  unsigned short* Qb  = wob + WE;      // Q | K | Vt | AO contiguous
  unsigned short* AO  = Qb + 3 * NE;

  const long TOT = 2 * NE + 4 * WE;          // cvt elements (12.6M)
  const long MBE = (long)CB * CS * CS;       // mbias elements (8.4M)
  const long needShorts = 8 * NE + 4 * WE;   // fused layout total (75.5 MB)
  const bool fused = ws_size >= (size_t)needShorts * 2;

  dim3 ggq(32, 24), gb(256, 1, 1);
  if (fused) {
    unsigned short* mb16 = AO + NE;  // fresh region (mbias written BEFORE gemm consumes xb)
    prep_all<<<(int)((TOT + MBE) / 2048), 256, 0, stream>>>(x, kv, WQw, WKw, WVw, WOw, xb,
                                                            ab, mask, mb16);
    gemm_qkv<<<ggq, gb, 0, stream>>>(xb, kvb, wqb, WQb, WKb, WVb, Qb);
    attn_kernel<<<dim3(CH, CS / 128, CB), 256, 0, stream>>>(
        Qb, Qb + NE, Qb + 2 * NE, mb16, mask, AO);
  } else {
    unsigned short* mb16 = xb;  // aliases x|kv (dead after gemm_qkv)
    cvt_all<<<(int)(TOT / 2048), 256, 0, stream>>>(x, kv, WQw, WKw, WVw, WOw, xb);
    gemm_qkv<<<ggq, gb, 0, stream>>>(xb, kvb, wqb, WQb, WKb, WVb, Qb);
    mk_mbias<<<(int)(MBE / 2048), 256, 0, stream>>>(ab, mask, mb16);
    attn_kernel<<<dim3(CH, CS / 128, CB), 256, 0, stream>>>(
        Qb, Qb + NE, Qb + 2 * NE, mb16, mask, AO);
  }

  gemm_wo<<<dim3(32, 16), gb, 0, stream>>>(AO, wob, WOb, out);
}

// Round 15
// 136.364 us; speedup vs baseline: 1.1019x; 1.0492x over previous
//
#include <hip/hip_runtime.h>

#define DEV static __device__ __forceinline__

typedef __attribute__((ext_vector_type(8))) __bf16 bf16x8;
typedef __attribute__((ext_vector_type(4))) float f32x4;

constexpr int CB = 2;     // batch
constexpr int CS = 2048;  // seq
constexpr int CE = 1024;  // embed
constexpr int CH = 16;    // heads
constexpr int CD = 64;    // head dim
constexpr float LOG2E = 1.44269504f;

DEV unsigned short f2bf(float x) {  // RNE f32 -> bf16 bits
  unsigned int u = __float_as_uint(x);
  u += 0x7fffu + ((u >> 16) & 1u);
  return (unsigned short)(u >> 16);
}

DEV f32x4 mfma32(bf16x8 a, bf16x8 b, f32x4 c) {  // 16x16x32
  return __builtin_amdgcn_mfma_f32_16x16x32_bf16(a, b, c, 0, 0, 0);
}

DEV unsigned int cvtpk(float lo, float hi) {  // pack 2 f32 -> 2 bf16 (RNE)
  unsigned int r;
  asm("v_cvt_pk_bf16_f32 %0, %1, %2" : "=v"(r) : "v"(lo), "v"(hi));
  return r;
}

DEV float exp2r(float x) {  // raw v_exp_f32
#if __has_builtin(__builtin_amdgcn_exp2f)
  return __builtin_amdgcn_exp2f(x);
#else
  float r; asm("v_exp_f32 %0, %1" : "=v"(r) : "v"(x)); return r;
#endif
}

DEV f32x4 unpk(unsigned int a, unsigned int b) {  // 4 packed bf16 -> f32x4
  f32x4 r;
  r[0] = __uint_as_float(a << 16);
  r[1] = __uint_as_float(a & 0xffff0000u);
  r[2] = __uint_as_float(b << 16);
  r[3] = __uint_as_float(b & 0xffff0000u);
  return r;
}

DEV void stage16(const void* g, void* l) {  // async global(16B/lane) -> LDS
  __builtin_amdgcn_global_load_lds(
      (const __attribute__((address_space(1))) unsigned int*)g,
      (__attribute__((address_space(3))) unsigned int*)l, 16, 0, 0);
}

// ---- elementwise bodies ----
DEV void cvt_body(long i, const float* __restrict__ x, const float* __restrict__ kv,
                  const float* __restrict__ w0, const float* __restrict__ w1,
                  const float* __restrict__ w2, const float* __restrict__ w3,
                  unsigned short* __restrict__ out) {
  const long NE = (long)CB * CS * CE;
  const long WE = (long)CE * CE;
  const float* src;
  long off = i;
  if (i < NE) {
    src = x;
  } else if (i < 2 * NE) {
    src = kv; off = i - NE;
  } else {
    long j = i - 2 * NE;
    int wi = (int)(j >> 20);
    src = wi == 0 ? w0 : wi == 1 ? w1 : wi == 2 ? w2 : w3;
    off = j & (WE - 1);
  }
  float4 a = *reinterpret_cast<const float4*>(src + off);
  float4 b = *reinterpret_cast<const float4*>(src + off + 4);
  uint4 v;
  v.x = (unsigned int)f2bf(a.x) | ((unsigned int)f2bf(a.y) << 16);
  v.y = (unsigned int)f2bf(a.z) | ((unsigned int)f2bf(a.w) << 16);
  v.z = (unsigned int)f2bf(b.x) | ((unsigned int)f2bf(b.y) << 16);
  v.w = (unsigned int)f2bf(b.z) | ((unsigned int)f2bf(b.w) << 16);
  *reinterpret_cast<uint4*>(out + i) = v;
}

DEV void mbias_body(long idx, const float* __restrict__ bias, const int* __restrict__ mask,
                    unsigned short* __restrict__ mb16) {
  const int b = (int)(idx >> 22);
  const int q = (int)((idx >> 11) & (CS - 1));
  const int k0 = (int)(idx & (CS - 1));
  const bool mq = mask[b * CS + q] != 0;
  const int4 mk0 = *reinterpret_cast<const int4*>(mask + b * CS + k0);
  const int4 mk1 = *reinterpret_cast<const int4*>(mask + b * CS + k0 + 4);
  const float4 b0 = *reinterpret_cast<const float4*>(bias + idx);
  const float4 b1 = *reinterpret_cast<const float4*>(bias + idx + 4);
  const float NEG = -1e9f * LOG2E;
  float v[8];
  if (mq) {
    v[0] = (mk0.x != 0) ? b0.x * LOG2E : NEG;
    v[1] = (mk0.y != 0) ? b0.y * LOG2E : NEG;
    v[2] = (mk0.z != 0) ? b0.z * LOG2E : NEG;
    v[3] = (mk0.w != 0) ? b0.w * LOG2E : NEG;
    v[4] = (mk1.x != 0) ? b1.x * LOG2E : NEG;
    v[5] = (mk1.y != 0) ? b1.y * LOG2E : NEG;
    v[6] = (mk1.z != 0) ? b1.z * LOG2E : NEG;
    v[7] = (mk1.w != 0) ? b1.w * LOG2E : NEG;
  } else {
#pragma unroll
    for (int j = 0; j < 8; j++) v[j] = 0.f;
  }
  uint4 o;
  o.x = cvtpk(v[0], v[1]); o.y = cvtpk(v[2], v[3]);
  o.z = cvtpk(v[4], v[5]); o.w = cvtpk(v[6], v[7]);
  *reinterpret_cast<uint4*>(mb16 + idx) = o;
}

__global__ __launch_bounds__(256) void prep_all(const float* __restrict__ x,
                                                const float* __restrict__ kv,
                                                const float* __restrict__ w0,
                                                const float* __restrict__ w1,
                                                const float* __restrict__ w2,
                                                const float* __restrict__ w3,
                                                unsigned short* __restrict__ outcvt,
                                                const float* __restrict__ bias,
                                                const int* __restrict__ mask,
                                                unsigned short* __restrict__ mb16) {
  const long CVTB = (2 * (long)CB * CS * CE + 4 * (long)CE * CE) / 2048;  // 6144
  if (blockIdx.x < CVTB) {
    cvt_body(((long)blockIdx.x * 256 + threadIdx.x) * 8, x, kv, w0, w1, w2, w3, outcvt);
  } else {
    mbias_body(((long)(blockIdx.x - CVTB) * 256 + threadIdx.x) * 8, bias, mask, mb16);
  }
}

__global__ __launch_bounds__(256) void cvt_all(const float* __restrict__ x,
                                               const float* __restrict__ kv,
                                               const float* __restrict__ w0,
                                               const float* __restrict__ w1,
                                               const float* __restrict__ w2,
                                               const float* __restrict__ w3,
                                               unsigned short* __restrict__ out) {
  cvt_body(((long)blockIdx.x * 256 + threadIdx.x) * 8, x, kv, w0, w1, w2, w3, out);
}
__global__ __launch_bounds__(256) void mk_mbias(const float* __restrict__ bias,
                                                const int* __restrict__ mask,
                                                unsigned short* __restrict__ mb16) {
  mbias_body(((long)blockIdx.x * 256 + threadIdx.x) * 8, bias, mask, mb16);
}

// ---------------- QKV GEMM v2: 256x256 tile, BK=32, phase-pipelined counted-vmcnt ----------------
// 512 thr / 8 waves (2x4); wave tile 128x64 = acc[8][4]. LDS 64KB: A,B each 2buf x 256x32 bf16
// swizzled (byte ^= ((row>>3)&1)<<5; pre-swizzled global src, swizzled ds_read).
// Per K-tile 2 phases x 16 MFMA. Stage: phase0 -> A(t+1) (2 loads), phase1 -> B(t+2) (2 loads).
// Waits: vmcnt(4) at phase0-close (A-R1(t) landed), vmcnt(3) at phase1-close (A-R0/B of t+1).
// Never drains to 0; junk-stages past K keep counts uniform (valid ws memory).
__global__ __launch_bounds__(512) void gemm_qkv(const unsigned short* __restrict__ xb,
                                                const unsigned short* __restrict__ kvb,
                                                const unsigned short* __restrict__ Wall,
                                                const float* __restrict__ bq,
                                                const float* __restrict__ bk,
                                                const float* __restrict__ bv,
                                                unsigned short* __restrict__ Qb) {
  __shared__ __align__(16) unsigned char ldsA[32768];  // 2 x 16KB
  __shared__ __align__(16) unsigned char ldsB[32768];
  const long NE = (long)CB * CS * CE;
  const long WE = (long)CE * CE;
  const int which = blockIdx.y >> 2;          // 0=Q 1=K 2=V
  const int n0 = (blockIdx.y & 3) * 256;
  const int m0 = blockIdx.x * 256;
  const unsigned char* Ab = (const unsigned char*)(which == 0 ? xb : kvb);
  const unsigned char* Bb = (const unsigned char*)(Wall + (long)which * WE);
  const float* bias = which == 0 ? bq : which == 1 ? bk : bv;

  const int tid = threadIdx.x;
  const int lane = tid & 63, w = tid >> 6;
  const int wr = w >> 2, wc = w & 3;
  const int g = lane >> 4, rr = lane & 15;

  // staging source pointers (per-thread, pre-swizzled col; advance 64B per stage)
  const int srow = tid >> 2;                                   // 0..127
  const int scsw = ((tid & 3) * 16) ^ (((tid >> 5) & 1) << 5); // inverse-swizzled col byte
  const unsigned char* apR0 = Ab + ((long)(m0 + srow) * CE) * 2 + scsw;
  const unsigned char* apR1 = Ab + ((long)(m0 + 128 + srow) * CE) * 2 + scsw;
  const unsigned char* bpR0 = Bb + ((long)(n0 + srow) * CE) * 2 + scsw;
  const unsigned char* bpR1 = Bb + ((long)(n0 + 128 + srow) * CE) * 2 + scsw;

  // ds_read per-thread bases (swizzled)
  const int cswz = (g * 16) ^ (((rr >> 3) & 1) << 5);
  const unsigned char* rbA = ldsA + wr * 8192 + rr * 64 + cswz;
  const unsigned char* rbB = ldsB + wc * 4096 + rr * 64 + cswz;

  f32x4 acc[8][4] = {};

  auto stA = [&](int buf) {  // A(t+1) both regions -> buf (2 loads)
    stage16(apR0, ldsA + buf * 16384 + w * 1024);
    stage16(apR1, ldsA + buf * 16384 + 8192 + w * 1024);
    apR0 += 64; apR1 += 64;
  };
  auto stB = [&](int buf) {  // B(t+2) both regions -> buf (2 loads)
    stage16(bpR0, ldsB + buf * 16384 + w * 1024);
    stage16(bpR1, ldsB + buf * 16384 + 8192 + w * 1024);
    bpR0 += 64; bpR1 += 64;
  };

  // prologue: queue = [B(0):2][A(0):2][B(1):2]
  stB(0);
  stA(0);
  stB(1);
  asm volatile("s_waitcnt vmcnt(3)" ::: "memory");  // A-R0(0)+B(0) landed
  __builtin_amdgcn_s_barrier();

  auto group = [&](int buf) {  // one K-tile in `buf`
    bf16x8 ar[4], br[4];
    // ---- phase 0: i 0-3 x j 0-3 ----
#pragma unroll
    for (int ii = 0; ii < 4; ii++)
      ar[ii] = *reinterpret_cast<const bf16x8*>(rbA + buf * 16384 + ii * 1024);
#pragma unroll
    for (int j = 0; j < 4; j++)
      br[j] = *reinterpret_cast<const bf16x8*>(rbB + buf * 16384 + j * 1024);
    stA(buf ^ 1);                                     // A(t+1)
    __builtin_amdgcn_s_barrier();                     // mid
    asm volatile("s_waitcnt lgkmcnt(0)" ::: "memory");
    __builtin_amdgcn_sched_barrier(0);
    __builtin_amdgcn_s_setprio(1);
#pragma unroll
    for (int ii = 0; ii < 4; ii++)
#pragma unroll
      for (int j = 0; j < 4; j++)
        acc[ii][j] = mfma32(ar[ii], br[j], acc[ii][j]);
    __builtin_amdgcn_s_setprio(0);
    asm volatile("s_waitcnt vmcnt(4)" ::: "memory");  // A-R1(t) landed (all waves before barrier)
    __builtin_amdgcn_s_barrier();                     // close phase 0
    // ---- phase 1: i 4-7 x j 0-3 ----
#pragma unroll
    for (int ii = 0; ii < 4; ii++)
      ar[ii] = *reinterpret_cast<const bf16x8*>(rbA + buf * 16384 + 4096 + ii * 1024);
    stB(buf);                                         // B(t+2)
    __builtin_amdgcn_s_barrier();                     // mid
    asm volatile("s_waitcnt lgkmcnt(0)" ::: "memory");
    __builtin_amdgcn_sched_barrier(0);
    __builtin_amdgcn_s_setprio(1);
#pragma unroll
    for (int ii = 0; ii < 4; ii++)
#pragma unroll
      for (int j = 0; j < 4; j++)
        acc[4 + ii][j] = mfma32(ar[ii], br[j], acc[4 + ii][j]);
    __builtin_amdgcn_s_setprio(0);
    asm volatile("s_waitcnt vmcnt(3)" ::: "memory");  // next tile's A-R0 + B landed
    __builtin_amdgcn_s_barrier();                     // close phase 1 (= next group head)
  };

#pragma unroll 1
  for (int it = 0; it < 16; ++it) {  // 32 K-tiles of 32
    group(0);
    group(1);
  }
  asm volatile("s_waitcnt vmcnt(0)" ::: "memory");  // drain junk stages

  // ---- epilogue ----
  const float scale = which == 0 ? 0.125f * LOG2E : 1.0f;
#pragma unroll
  for (int i = 0; i < 8; i++) {
#pragma unroll
    for (int j = 0; j < 4; j++) {
      const int colg = n0 + wc * 64 + j * 16 + rr;
      const float bvv = bias[colg];
      if (which == 2) {  // V^T layout [B,H,DK,S]
        const int rowbase = m0 + wr * 128 + i * 16 + g * 4;
        const int bb = rowbase >> 11, s = rowbase & 2047;
        const int hh = colg >> 6, d = colg & 63;
        uint2 val;
        val.x = (unsigned int)f2bf(acc[i][j][0] + bvv) | ((unsigned int)f2bf(acc[i][j][1] + bvv) << 16);
        val.y = (unsigned int)f2bf(acc[i][j][2] + bvv) | ((unsigned int)f2bf(acc[i][j][3] + bvv) << 16);
        *reinterpret_cast<uint2*>(Qb + 2 * NE + ((long)((bb * CH + hh) * CD + d)) * CS + s) = val;
      } else {
        unsigned short* outp = Qb + (long)which * NE;
#pragma unroll
        for (int r = 0; r < 4; r++) {
          const int row = m0 + wr * 128 + i * 16 + g * 4 + r;
          outp[(long)row * CE + colg] = f2bf((acc[i][j][r] + bvv) * scale);
        }
      }
    }
  }
}

// ---------------- WO GEMM: 128x64 tile, 512 blocks (2/CU) ----------------
__global__ __launch_bounds__(256) void gemm_wo(const unsigned short* __restrict__ A,
                                               const unsigned short* __restrict__ W,
                                               const float* __restrict__ bias,
                                               float* __restrict__ out) {
  __shared__ __align__(16) unsigned short As[128 * 64];
  __shared__ __align__(16) unsigned short Bs[64 * 64];
  const int tid = threadIdx.x;
  const int lane = tid & 63, wave = tid >> 6;
  const int wm = (wave >> 1) * 64, wn = (wave & 1) * 32;
  const int g = lane >> 4, rr = lane & 15;
  const int m0 = blockIdx.x * 128, n0 = blockIdx.y * 64;
  const int K = CE;
  f32x4 acc[4][2] = {};

  for (int k0 = 0; k0 < K; k0 += 64) {
#pragma unroll
    for (int t = 0; t < 4; t++) {
      const int u = t * 256 + tid;
      const int row = u >> 3, ce = (u & 7) * 8;
      stage16(A + (long)(m0 + row) * K + k0 + ce, (char*)As + (t * 256 + (tid & 192)) * 16);
    }
#pragma unroll
    for (int t = 0; t < 2; t++) {
      const int u = t * 256 + tid;
      const int row = u >> 3, ce = (u & 7) * 8;
      stage16(W + (long)(n0 + row) * K + k0 + ce, (char*)Bs + (t * 256 + (tid & 192)) * 16);
    }
    __syncthreads();
#pragma unroll
    for (int kk = 0; kk < 2; kk++) {
      bf16x8 af[4], bfr[2];
#pragma unroll
      for (int i = 0; i < 4; i++)
        af[i] = *reinterpret_cast<const bf16x8*>(&As[(wm + i * 16 + rr) * 64 + kk * 32 + g * 8]);
#pragma unroll
      for (int j = 0; j < 2; j++)
        bfr[j] = *reinterpret_cast<const bf16x8*>(&Bs[(wn + j * 16 + rr) * 64 + kk * 32 + g * 8]);
#pragma unroll
      for (int i = 0; i < 4; i++)
#pragma unroll
        for (int j = 0; j < 2; j++)
          acc[i][j] = mfma32(af[i], bfr[j], acc[i][j]);
    }
    __syncthreads();
  }

#pragma unroll
  for (int i = 0; i < 4; i++)
#pragma unroll
    for (int j = 0; j < 2; j++) {
      const int colg = n0 + wn + j * 16 + rr;
      const float bvv = bias[colg];
#pragma unroll
      for (int r = 0; r < 4; r++) {
        const int row = m0 + wm + i * 16 + g * 4 + r;
        out[(long)row * CE + colg] = acc[i][j][r] + bvv;
      }
    }
}

// ---------------- Flash attention v12: BK=128, static softmax (unchanged) ----------------
__global__ __launch_bounds__(256, 2) void attn_kernel(const unsigned short* __restrict__ Qb,
                                                      const unsigned short* __restrict__ Kb,
                                                      const unsigned short* __restrict__ Vtw,
                                                      const unsigned short* __restrict__ mb16,
                                                      const int* __restrict__ mask,
                                                      unsigned short* __restrict__ AO) {
  __shared__ __align__(16) unsigned char lds[65536];
  const int h = blockIdx.x, qt = blockIdx.y, b = blockIdx.z;
  const int tid = threadIdx.x;
  const int lane = tid & 63, w = tid >> 6;
  const int g = lane >> 4, c = lane & 15;
  const int qbase = qt * 128 + w * 32;

  bf16x8 qf[2][2];
#pragma unroll
  for (int qb = 0; qb < 2; qb++) {
    const unsigned short* Qrow = Qb + ((long)b * CS + qbase + qb * 16 + c) * CE + h * CD;
    qf[qb][0] = *reinterpret_cast<const bf16x8*>(Qrow + g * 8);
    qf[qb][1] = *reinterpret_cast<const bf16x8*>(Qrow + 32 + g * 8);
    if (mask[b * CS + qbase + qb * 16 + c] == 0) {
      qf[qb][0] = bf16x8{}; qf[qb][1] = bf16x8{};
    }
  }

  const unsigned char *kg[4], *vg[4];
  {
    const unsigned char* Ksrc = (const unsigned char*)(Kb + (long)b * CS * CE + h * CD);
    const unsigned char* Vsrc = (const unsigned char*)(Vtw + (long)(b * CH + h) * CD * CS);
    const int rr8 = lane >> 3;
    const int csw = ((lane & 7) << 4) ^ (rr8 << 4);
#pragma unroll
    for (int t = 0; t < 4; t++) {
      const int krow = t * 32 + w * 8 + rr8;
      const int key = (krow & 96) + ((krow >> 2) & 3) * 8 + ((krow >> 4) & 1) * 4 + (krow & 3);
      kg[t] = Ksrc + (long)key * (CE * 2) + csw;
      const int vrow = (t & 1) * 32 + w * 8 + rr8;
      vg[t] = Vsrc + (long)vrow * (CS * 2) + (t >> 1) * 128 + csw;
    }
  }
  const int sw = (c & 7) << 4;
  const unsigned char* rb0 = lds + c * 128 + ((g * 16) ^ sw);
  const unsigned char* rb1 = lds + c * 128 + ((64 + g * 16) ^ sw);

  const unsigned short* mbp0 = mb16 + ((long)b * CS + qbase + c) * CS + g * 8;
  const unsigned short* mbp1 = mb16 + ((long)b * CS + qbase + 16 + c) * CS + g * 8;

  f32x4 o[2][4] = {};
  f32x4 lsum4[2] = {};
  uint4 mbr[2][4];

  auto stage = [&](int bo) {
    unsigned char* kbuf = lds + bo;
    unsigned char* vbuf = lds + bo + 16384;
#pragma unroll
    for (int t = 0; t < 4; t++) {
      stage16(kg[t], kbuf + t * 4096 + w * 1024);
      stage16(vg[t], vbuf + (t >> 1) * 8192 + (t & 1) * 4096 + w * 1024);
      kg[t] += 128 * CE * 2;
      vg[t] += 128 * 2;
    }
  };
  auto load_mb = [&](bool adv) {
#pragma unroll
    for (int kb = 0; kb < 4; kb++) {
      mbr[0][kb] = *reinterpret_cast<const uint4*>(mbp0 + kb * 32);
      mbr[1][kb] = *reinterpret_cast<const uint4*>(mbp1 + kb * 32);
    }
    if (adv) { mbp0 += 128; mbp1 += 128; }
  };

  auto compute = [&](int bo, bool adv) {
    f32x4 sf[2][8];
    __builtin_amdgcn_s_setprio(1);
#pragma unroll
    for (int cb = 0; cb < 8; cb++) {
      const bf16x8 kf0 = *reinterpret_cast<const bf16x8*>(rb0 + bo + cb * 2048);
      const bf16x8 kf1 = *reinterpret_cast<const bf16x8*>(rb1 + bo + cb * 2048);
#pragma unroll
      for (int qb = 0; qb < 2; qb++) {
        const uint4 m = mbr[qb][cb >> 1];
        const f32x4 ci = (cb & 1) ? unpk(m.z, m.w) : unpk(m.x, m.y);
        f32x4 t = mfma32(kf0, qf[qb][0], ci);
        sf[qb][cb] = mfma32(kf1, qf[qb][1], t);
      }
    }
    __builtin_amdgcn_s_setprio(0);
    load_mb(adv);
    uint4 pw[2][4];
#pragma unroll
    for (int qb = 0; qb < 2; qb++)
#pragma unroll
      for (int kb = 0; kb < 4; kb++)
#pragma unroll
        for (int half = 0; half < 2; half++) {
          const int cb = 2 * kb + half;
          f32x4 pv;
          pv[0] = exp2r(sf[qb][cb][0]);
          pv[1] = exp2r(sf[qb][cb][1]);
          pv[2] = exp2r(sf[qb][cb][2]);
          pv[3] = exp2r(sf[qb][cb][3]);
          lsum4[qb] = lsum4[qb] + pv;
          if (half == 0) { pw[qb][kb].x = cvtpk(pv[0], pv[1]); pw[qb][kb].y = cvtpk(pv[2], pv[3]); }
          else           { pw[qb][kb].z = cvtpk(pv[0], pv[1]); pw[qb][kb].w = cvtpk(pv[2], pv[3]); }
        }
    __builtin_amdgcn_s_setprio(1);
#pragma unroll
    for (int nb = 0; nb < 4; nb++) {
#pragma unroll
      for (int kb = 0; kb < 4; kb++) {
        const unsigned char* rbx = (kb & 1) ? rb1 : rb0;
        const bf16x8 vf = *reinterpret_cast<const bf16x8*>(
            rbx + bo + 16384 + (kb >> 1) * 8192 + nb * 2048);
#pragma unroll
        for (int qb = 0; qb < 2; qb++)
          o[qb][nb] = mfma32(vf, __builtin_bit_cast(bf16x8, pw[qb][kb]), o[qb][nb]);
      }
    }
    __builtin_amdgcn_s_setprio(0);
  };

  stage(0);
  load_mb(true);
  stage(32768);

#pragma unroll 1
  for (int it = 0; it < 8; ++it) {
    asm volatile("s_waitcnt vmcnt(16)" ::: "memory");
    __builtin_amdgcn_s_barrier();
    __builtin_amdgcn_sched_barrier(0);
    compute(0, it < 7);
    __builtin_amdgcn_sched_barrier(0);
    __builtin_amdgcn_s_barrier();
    stage(0);
    asm volatile("s_waitcnt vmcnt(16)" ::: "memory");
    __builtin_amdgcn_s_barrier();
    __builtin_amdgcn_sched_barrier(0);
    compute(32768, it < 7);
    __builtin_amdgcn_sched_barrier(0);
    __builtin_amdgcn_s_barrier();
    stage(32768);
  }

#pragma unroll
  for (int qb = 0; qb < 2; qb++) {
    float lsum = (lsum4[qb][0] + lsum4[qb][1]) + (lsum4[qb][2] + lsum4[qb][3]);
    lsum += __shfl_xor(lsum, 16, 64);
    lsum += __shfl_xor(lsum, 32, 64);
    const float linv = 1.0f / lsum;
    unsigned short* Orow = AO + ((long)b * CS + qbase + qb * 16 + c) * CE + h * CD;
#pragma unroll
    for (int nb = 0; nb < 4; nb++) {
      uint2 val;
      val.x = (unsigned int)f2bf(o[qb][nb][0] * linv) | ((unsigned int)f2bf(o[qb][nb][1] * linv) << 16);
      val.y = (unsigned int)f2bf(o[qb][nb][2] * linv) | ((unsigned int)f2bf(o[qb][nb][3] * linv) << 16);
      *reinterpret_cast<uint2*>(Orow + nb * 16 + g * 4) = val;
    }
  }
  asm volatile("s_waitcnt vmcnt(0)" ::: "memory");
}

// ---------------- host ----------------
extern "C" void kernel_launch(void* const* d_in, const int* in_sizes, int n_in,
                              void* d_out, int out_size, void* d_ws, size_t ws_size,
                              hipStream_t stream) {
  (void)in_sizes; (void)n_in; (void)out_size;
  const float* x    = (const float*)d_in[0];
  const float* kv   = (const float*)d_in[1];
  const int*   mask = (const int*)d_in[2];
  const float* ab   = (const float*)d_in[3];
  const float* WQw  = (const float*)d_in[4];
  const float* WQb  = (const float*)d_in[5];
  const float* WKw  = (const float*)d_in[6];
  const float* WKb  = (const float*)d_in[7];
  const float* WVw  = (const float*)d_in[8];
  const float* WVb  = (const float*)d_in[9];
  const float* WOw  = (const float*)d_in[10];
  const float* WOb  = (const float*)d_in[11];
  float* out = (float*)d_out;

  const long NE = (long)CB * CS * CE;  // 4,194,304
  const long WE = (long)CE * CE;       // 1,048,576
  unsigned short* ws  = (unsigned short*)d_ws;
  unsigned short* xb  = ws;            // [x | kv | WQ | WK | WV | WO] contiguous
  unsigned short* kvb = xb + NE;
  unsigned short* wqb = kvb + NE;      // WQ|WK|WV contiguous = Wall
  unsigned short* wob = wqb + 3 * WE;
  unsigned short* Qb  = wob + WE;      // Q | K | Vt | AO contiguous
  unsigned short* AO  = Qb + 3 * NE;

  const long TOT = 2 * NE + 4 * WE;          // cvt elements
  const long MBE = (long)CB * CS * CS;       // mbias elements
  const long needShorts = 8 * NE + 4 * WE;   // fused layout total (75.5 MB)
  const bool fused = ws_size >= (size_t)needShorts * 2;

  if (fused) {
    unsigned short* mb16 = AO + NE;
    prep_all<<<(int)((TOT + MBE) / 2048), 256, 0, stream>>>(x, kv, WQw, WKw, WVw, WOw, xb,
                                                            ab, mask, mb16);
    gemm_qkv<<<dim3(16, 12), 512, 0, stream>>>(xb, kvb, wqb, WQb, WKb, WVb, Qb);
    attn_kernel<<<dim3(CH, CS / 128, CB), 256, 0, stream>>>(
        Qb, Qb + NE, Qb + 2 * NE, mb16, mask, AO);
  } else {
    unsigned short* mb16 = xb;
    cvt_all<<<(int)(TOT / 2048), 256, 0, stream>>>(x, kv, WQw, WKw, WVw, WOw, xb);
    gemm_qkv<<<dim3(16, 12), 512, 0, stream>>>(xb, kvb, wqb, WQb, WKb, WVb, Qb);
    mk_mbias<<<(int)(MBE / 2048), 256, 0, stream>>>(ab, mask, mb16);
    attn_kernel<<<dim3(CH, CS / 128, CB), 256, 0, stream>>>(
        Qb, Qb + NE, Qb + 2 * NE, mb16, mask, AO);
  }

  gemm_wo<<<dim3(32, 16), 256, 0, stream>>>(AO, wob, WOb, out);
}